// Round 5
// baseline (292.705 us; speedup 1.0000x reference)
//
#include <hip/hip_runtime.h>
#include <hip/hip_cooperative_groups.h>
#include <stdint.h>

namespace cg = cooperative_groups;

// Problem constants: B=2, T=512, P=8, D=1024, NH=16, NKV=4, HD=64
// Rows (b,p,t): 16*512 = 8192.

typedef __attribute__((ext_vector_type(8))) short bf16x8;
typedef __attribute__((ext_vector_type(4))) float f32x4;
typedef __attribute__((ext_vector_type(16))) float f32x16;
typedef __attribute__((ext_vector_type(4))) unsigned short us4;
typedef __attribute__((ext_vector_type(8))) unsigned short us8;

static __device__ __forceinline__ unsigned short f2bf(float f) {
  unsigned u = __float_as_uint(f);
  u += 0x7fffu + ((u >> 16) & 1u);   // RNE
  return (unsigned short)(u >> 16);
}

static __device__ __forceinline__ void ld_lds16(const void* g, void* l) {
  __builtin_amdgcn_global_load_lds(
      (const __attribute__((address_space(1))) void*)g,
      (__attribute__((address_space(3))) void*)l, 16, 0, 0);
}

static __device__ __forceinline__ f32x4 mfma16(bf16x8 a, bf16x8 b, f32x4 c) {
  return __builtin_amdgcn_mfma_f32_16x16x32_bf16(a, b, c, 0, 0, 0);
}
static __device__ __forceinline__ f32x16 mfma32(bf16x8 a, bf16x8 b, f32x16 c) {
  return __builtin_amdgcn_mfma_f32_32x32x16_bf16(a, b, c, 0, 0, 0);
}

// ---- single cooperative kernel: conv -> QKV GEMM -> attn -> O GEMM ------
// 256 blocks x 512 thr, 128 KiB LDS => 1 block/CU, all co-resident.
// Rationale (r4 post-mortem): 4 dispatches + harness fill at ~10us launch
// overhead each explain the ~50us gap between kernel-sum (~90us) and
// dur_us (~180us). grid.sync() replaces 3 launches; stage bodies are the
// r3/r4-verified ones, unchanged.
__global__ __launch_bounds__(512, 2) void mega(
    const float* __restrict__ hs, const float* __restrict__ Wq,
    const float* __restrict__ Wk, const float* __restrict__ Wv,
    const float* __restrict__ Wo,
    unsigned short* __restrict__ xb, unsigned short* __restrict__ wqkv,
    unsigned short* __restrict__ wot, unsigned short* __restrict__ qb,
    unsigned short* __restrict__ kb, unsigned short* __restrict__ vtb,
    float* __restrict__ out) {
  __shared__ __align__(16) unsigned char LDSb[131072];   // 128 KiB, re-aliased
  cg::grid_group grid = cg::this_grid();
  int bid = blockIdx.x, tid = threadIdx.x;

  // ================= stage A: conversions ==================================
  {
    float (*tile)[65] = (float(*)[65])LDSb;
    // W transpose: 640 64x64 tiles, 3 rounds of 256 blocks (tid<256 active).
    for (int i = 0; i < 3; ++i) {
      int tb = i * 256 + bid;
      bool act = (tb < 640) && (tid < 256);
      const float* W = nullptr; unsigned short* Wt = nullptr;
      int N = 0, tc0 = 0, tn0 = 0;
      if (act) {
        if (tb < 256)      { W = Wq; Wt = wqkv;                       N = 1024; tc0 = (tb >> 4) * 64;          tn0 = (tb & 15) * 64; }
        else if (tb < 320) { W = Wk; Wt = wqkv + (size_t)1024 * 1024; N = 256;  tc0 = ((tb - 256) >> 2) * 64;  tn0 = ((tb - 256) & 3) * 64; }
        else if (tb < 384) { W = Wv; Wt = wqkv + (size_t)1280 * 1024; N = 256;  tc0 = ((tb - 320) >> 2) * 64;  tn0 = ((tb - 320) & 3) * 64; }
        else               { W = Wo; Wt = wot;                        N = 1024; tc0 = ((tb - 384) >> 4) * 64;  tn0 = ((tb - 384) & 15) * 64; }
      }
      int tr = tid >> 4, tc = tid & 15;
      if (act) {
#pragma unroll
        for (int k = 0; k < 4; ++k) {
          int c = tr + k * 16;
          float4 v = *(const float4*)(W + (size_t)(tc0 + c) * N + tn0 + tc * 4);
          tile[c][tc * 4 + 0] = v.x; tile[c][tc * 4 + 1] = v.y;
          tile[c][tc * 4 + 2] = v.z; tile[c][tc * 4 + 3] = v.w;
        }
      }
      __syncthreads();
      if (act) {
#pragma unroll
        for (int k = 0; k < 4; ++k) {
          int n = tr + k * 16;
          us4 o;
          o.x = f2bf(tile[tc * 4 + 0][n]); o.y = f2bf(tile[tc * 4 + 1][n]);
          o.z = f2bf(tile[tc * 4 + 2][n]); o.w = f2bf(tile[tc * 4 + 3][n]);
          *(us4*)(Wt + (size_t)(tn0 + n) * 1024 + tc0 + tc * 4) = o;
        }
      }
      __syncthreads();
    }
    // x pack: (B,T,P,D) f32 -> (B,P,T,D) bf16, 2M float4s over 256x512x16.
    for (int it = 0; it < 16; ++it) {
      int gid = it * 131072 + bid * 512 + tid;
      size_t e = (size_t)gid * 4;
      int r = (int)(e >> 10);          // bp*512 + t
      int d = (int)(e & 1023);
      int b = r >> 12, p = (r >> 9) & 7, t = r & 511;
      const float4* src = (const float4*)(hs + ((((size_t)b * 512 + t) * 8 + p) << 10) + d);
      float4 v = *src;
      us4 o;
      o.x = f2bf(v.x); o.y = f2bf(v.y); o.z = f2bf(v.z); o.w = f2bf(v.w);
      *(us4*)(xb + e) = o;
    }
  }
  grid.sync();

  // ================= stage B: 256x256xK=1024 QKV GEMM (192 tiles) =========
  if (bid < 192) {
    constexpr int K = 1024;
    constexpr int KT = K / 64;
    unsigned short* SmB = (unsigned short*)LDSb;         // [2][2][256*64]
    unsigned short* Cs = SmB;

    int lane = tid & 63, wid = tid >> 6;
    int quad = lane >> 4, lo = lane & 15;
    int wg = (bid & 7) * 24 + (bid >> 3);                // T1: 192 = 8 x 24
    int tn = wg % 6, tm = wg / 6;
    int wr = wid >> 2, wc = wid & 3;
    int srow = lane >> 3, schunk = lane & 7;
    int cg_ = schunk ^ srow;

    const unsigned short* pa = xb + ((size_t)(tm * 256) + wid * 8 + srow) * K + cg_ * 8;
    const unsigned short* pb = wqkv + ((size_t)(tn * 256) + wid * 8 + srow) * K + cg_ * 8;

    f32x4 z = {0.f, 0.f, 0.f, 0.f};
    f32x4 acc[8][4];
#pragma unroll
    for (int i = 0; i < 8; ++i)
#pragma unroll
      for (int j = 0; j < 4; ++j) acc[i][j] = z;

    auto stage = [&](int t, int p) {
#pragma unroll
      for (int i = 0; i < 4; ++i) {
        ld_lds16(pa + (size_t)i * 64 * K + t * 64,
                 (char*)(SmB + (size_t)p * 2 * 16384) + (wid * 8 + i * 64) * 128);
        ld_lds16(pb + (size_t)i * 64 * K + t * 64,
                 (char*)(SmB + (size_t)(p * 2 + 1) * 16384) + (wid * 8 + i * 64) * 128);
      }
    };

    stage(0, 0);
    stage(1, 1);
    asm volatile("s_waitcnt vmcnt(8)" ::: "memory");
    asm volatile("s_barrier" ::: "memory");

    bf16x8 af[4][2], bb0[2][2], bb1[2][2];

    for (int t = 0; t < KT; ++t) {
      int p = t & 1;
      const unsigned short* As = SmB + (size_t)p * 2 * 16384;
      const unsigned short* Bs = SmB + (size_t)(p * 2 + 1) * 16384;

      // P1: af half0 + bb half0; MFMA (m0,n0)
#pragma unroll
      for (int mi = 0; mi < 4; ++mi)
#pragma unroll
        for (int kx = 0; kx < 2; ++kx) {
          int row = wr * 128 + mi * 16 + lo;
          int cgx = (quad + kx * 4) ^ (row & 7);
          af[mi][kx] = *(const bf16x8*)(As + (size_t)row * 64 + cgx * 8);
        }
#pragma unroll
      for (int ni = 0; ni < 2; ++ni)
#pragma unroll
        for (int kx = 0; kx < 2; ++kx) {
          int row = wc * 64 + ni * 16 + lo;
          int cgx = (quad + kx * 4) ^ (row & 7);
          bb0[ni][kx] = *(const bf16x8*)(Bs + (size_t)row * 64 + cgx * 8);
        }
      asm volatile("s_barrier" ::: "memory");
      __builtin_amdgcn_s_setprio(1);
#pragma unroll
      for (int kx = 0; kx < 2; ++kx)
#pragma unroll
        for (int mi = 0; mi < 4; ++mi)
#pragma unroll
          for (int ni = 0; ni < 2; ++ni)
            acc[mi][ni] = mfma16(af[mi][kx], bb0[ni][kx], acc[mi][ni]);
      __builtin_amdgcn_s_setprio(0);
      asm volatile("s_barrier" ::: "memory");

      // P2: bb half1; MFMA (m0,n1)
#pragma unroll
      for (int ni = 0; ni < 2; ++ni)
#pragma unroll
        for (int kx = 0; kx < 2; ++kx) {
          int row = wc * 64 + (ni + 2) * 16 + lo;
          int cgx = (quad + kx * 4) ^ (row & 7);
          bb1[ni][kx] = *(const bf16x8*)(Bs + (size_t)row * 64 + cgx * 8);
        }
      asm volatile("s_barrier" ::: "memory");
      __builtin_amdgcn_s_setprio(1);
#pragma unroll
      for (int kx = 0; kx < 2; ++kx)
#pragma unroll
        for (int mi = 0; mi < 4; ++mi)
#pragma unroll
          for (int ni = 0; ni < 2; ++ni)
            acc[mi][ni + 2] = mfma16(af[mi][kx], bb1[ni][kx], acc[mi][ni + 2]);
      __builtin_amdgcn_s_setprio(0);
      asm volatile("s_barrier" ::: "memory");

      // P3: af half1 (overwrite); MFMA (m1,n1)
#pragma unroll
      for (int mi = 0; mi < 4; ++mi)
#pragma unroll
        for (int kx = 0; kx < 2; ++kx) {
          int row = wr * 128 + 64 + mi * 16 + lo;
          int cgx = (quad + kx * 4) ^ (row & 7);
          af[mi][kx] = *(const bf16x8*)(As + (size_t)row * 64 + cgx * 8);
        }
      asm volatile("s_barrier" ::: "memory");
      __builtin_amdgcn_s_setprio(1);
#pragma unroll
      for (int kx = 0; kx < 2; ++kx)
#pragma unroll
        for (int mi = 0; mi < 4; ++mi)
#pragma unroll
          for (int ni = 0; ni < 2; ++ni)
            acc[mi + 4][ni + 2] = mfma16(af[mi][kx], bb1[ni][kx], acc[mi + 4][ni + 2]);
      __builtin_amdgcn_s_setprio(0);
      asm volatile("s_barrier" ::: "memory");

      // P4: prefetch t+2; MFMA (m1,n0); counted vmcnt
      bool pf = (t + 2 < KT);
      if (pf) stage(t + 2, p);
      __builtin_amdgcn_s_setprio(1);
#pragma unroll
      for (int kx = 0; kx < 2; ++kx)
#pragma unroll
        for (int mi = 0; mi < 4; ++mi)
#pragma unroll
          for (int ni = 0; ni < 2; ++ni)
            acc[mi + 4][ni] = mfma16(af[mi][kx], bb0[ni][kx], acc[mi + 4][ni]);
      __builtin_amdgcn_s_setprio(0);
      if (pf) asm volatile("s_waitcnt vmcnt(8)" ::: "memory");
      else    asm volatile("s_waitcnt vmcnt(0)" ::: "memory");
      asm volatile("s_barrier" ::: "memory");
    }

    __syncthreads();

    // epilogue: C/D frag layout col = lane&15, row = quad*4 + r
    if (tn < 5) {
      float qscale = (tn < 4) ? 0.125f : 1.0f;
#pragma unroll
      for (int mi = 0; mi < 8; ++mi)
#pragma unroll
        for (int r = 0; r < 4; ++r) {
          int row = wr * 128 + mi * 16 + quad * 4 + r;
          int tpos = (tm * 256 + row) & 511;
#pragma unroll
          for (int ni = 0; ni < 2; ++ni) {
            float invf = exp2f((float)(ni * 16 + lo) * -0.41524101186092029f);
            float ang = (float)tpos * invf;
            float s, c;
            __sincosf(ang, &s, &c);
            float x1 = acc[mi][ni][r], x2 = acc[mi][ni + 2][r];
            acc[mi][ni][r]     = (x1 * c - x2 * s) * qscale;
            acc[mi][ni + 2][r] = (x1 * s + x2 * c) * qscale;
          }
        }
#pragma unroll
      for (int mi = 0; mi < 8; ++mi)
#pragma unroll
        for (int ni = 0; ni < 4; ++ni)
#pragma unroll
          for (int r = 0; r < 4; ++r) {
            int row = wr * 128 + mi * 16 + quad * 4 + r;
            int col = wc * 64 + ni * 16 + lo;
            int cs = col ^ (((row >> 2) & 3) << 3);
            Cs[row * 256 + cs] = f2bf(acc[mi][ni][r]);
          }
      __syncthreads();
      int tc = tid & 31, ro = tid >> 5;
#pragma unroll
      for (int it = 0; it < 16; ++it) {
        int row = ro + 16 * it;
        int cs = (tc * 8) ^ (((row >> 2) & 3) << 3);
        us8 v = *(const us8*)(Cs + row * 256 + cs);
        size_t grow = (size_t)(tm * 256 + row);
        if (tn < 4) *(us8*)(qb + grow * 1024 + tn * 256 + tc * 8) = v;
        else        *(us8*)(kb + grow * 256 + tc * 8) = v;
      }
    } else {
      // V^T: stage transposed into Cs[col][t-local], then coalesced stores.
#pragma unroll
      for (int mi = 0; mi < 8; ++mi)
#pragma unroll
        for (int ni = 0; ni < 4; ++ni)
#pragma unroll
          for (int r = 0; r < 4; ++r) {
            int trow = wr * 128 + mi * 16 + quad * 4 + r;
            int col = wc * 64 + ni * 16 + lo;
            Cs[col * 256 + (trow ^ ((col & 7) << 3))] = f2bf(acc[mi][ni][r]);
          }
      __syncthreads();
      int t0 = (tid & 31) * 8, colIdx = tid >> 5;
      int bp = tm >> 1, tbase = (tm & 1) * 256;
#pragma unroll
      for (int it = 0; it < 16; ++it) {
        int col = colIdx + it * 16;
        us8 v = *(const us8*)(Cs + col * 256 + (t0 ^ ((col & 7) << 3)));
        int hh = col >> 6, dd = col & 63;
        *(us8*)(vtb + (((size_t)(bp * 4 + hh)) * 64 + dd) * 512 + tbase + t0) = v;
      }
    }
  }
  grid.sync();

  // ================= stage C: attention (2 units/block) ====================
  {
    unsigned short* Qs = (unsigned short*)LDSb;            // 256*64
    unsigned short* KsB = Qs + 256 * 64;                   // 2 x 64*64
    unsigned short* VsB = KsB + 2 * 64 * 64;               // 2 x 64*64
    unsigned short* ao = xb;                               // alias (xb consumed)

    int lane = tid & 63, wid = tid >> 6;
    int lo32 = lane & 31, hl = lane >> 5;
    int srow = lane >> 3, schunk = lane & 7;

    for (int u = 0; u < 2; ++u) {
      __syncthreads();                                     // unit LDS handoff
      int uu = bid + u * 256;
      int wg = (uu & 7) * 64 + (uu >> 3);                  // T1 over 512 units
      int qt = wg & 1, bph = wg >> 1;
      int head = bph & 15, bp = bph >> 4;
      int kvh = head >> 2;
      int t0 = qt * 256;

      const unsigned short* qg = qb + ((size_t)(bp * 512 + t0)) * 1024 + head * 64;
      const unsigned short* kg = kb + ((size_t)bp * 512) * 256 + kvh * 64;
      const unsigned short* vg = vtb + ((size_t)(bp * 4 + kvh)) * 64 * 512;

#pragma unroll
      for (int i = 0; i < 4; ++i) {    // stage Q: 256 rows x 128B
        int row = wid * 8 + i * 64 + srow;
        int cg_ = schunk ^ (row & 7);
        ld_lds16(qg + (size_t)row * 1024 + cg_ * 8, (char*)Qs + (wid * 8 + i * 64) * 128);
      }

      auto stageKV = [&](int kt, int p) {
        int row = wid * 8 + srow;
        int cg_ = schunk ^ (row & 7);
        ld_lds16(kg + (size_t)(kt * 64 + row) * 256 + cg_ * 8, (char*)(KsB + p * 4096) + (wid * 8) * 128);
        ld_lds16(vg + (size_t)row * 512 + kt * 64 + cg_ * 8, (char*)(VsB + p * 4096) + (wid * 8) * 128);
      };

      stageKV(0, 0);
      stageKV(1, 1);
      asm volatile("s_waitcnt vmcnt(2)" ::: "memory");   // Q + tile0 landed
      asm volatile("s_barrier" ::: "memory");

      f32x16 z16 = {0.f};
      f32x16 o0 = z16, o1 = z16;
      float psum = 0.f;
      int qrow = wid * 32 + lo32;

      for (int kt = 0; kt < 8; ++kt) {
        int p = kt & 1;
        const unsigned short* Kp = KsB + p * 4096;
        const unsigned short* Vp = VsB + p * 4096;

        f32x16 st0 = z16, st1 = z16;
#pragma unroll
        for (int kkc = 0; kkc < 4; ++kkc) {
          int ch = 2 * kkc + hl;
          bf16x8 qf = *(const bf16x8*)(Qs + (size_t)qrow * 64 + ((ch ^ (qrow & 7)) * 8));
          bf16x8 kf0 = *(const bf16x8*)(Kp + (size_t)lo32 * 64 + ((ch ^ (lo32 & 7)) * 8));
          bf16x8 kf1 = *(const bf16x8*)(Kp + (size_t)(32 + lo32) * 64 + ((ch ^ (lo32 & 7)) * 8));
          st0 = mfma32(kf0, qf, st0);
          st1 = mfma32(kf1, qf, st1);
        }

#pragma unroll
        for (int t = 0; t < 2; ++t) {
          const f32x16& stv = t ? st1 : st0;
          unsigned pk[8], xpk[8];
#pragma unroll
          for (int pp = 0; pp < 8; ++pp) {
            float e0 = __expf(stv[2 * pp]);
            float e1 = __expf(stv[2 * pp + 1]);
            psum += e0 + e1;
            pk[pp] = ((__float_as_uint(e0) + 0x8000u) >> 16) |
                     ((__float_as_uint(e1) + 0x8000u) & 0xffff0000u);
          }
#pragma unroll
          for (int pp = 0; pp < 8; ++pp) xpk[pp] = (unsigned)__shfl_xor((int)pk[pp], 32);
#pragma unroll
          for (int cc = 0; cc < 2; ++cc) {
            int o = cc * 4;
            union { unsigned u[4]; bf16x8 v; } afr;
            if (hl == 0) {
              afr.u[0] = pk[o];      afr.u[1] = pk[o + 1];
              afr.u[2] = xpk[o];     afr.u[3] = xpk[o + 1];
            } else {
              afr.u[0] = xpk[o + 2]; afr.u[1] = xpk[o + 3];
              afr.u[2] = pk[o + 2];  afr.u[3] = pk[o + 3];
            }
            int vch = 2 * (t * 2 + cc) + hl;
            bf16x8 v0 = *(const bf16x8*)(Vp + (size_t)lo32 * 64 + ((vch ^ (lo32 & 7)) * 8));
            bf16x8 v1 = *(const bf16x8*)(Vp + (size_t)(32 + lo32) * 64 + ((vch ^ (lo32 & 7)) * 8));
            o0 = mfma32(afr.v, v0, o0);
            o1 = mfma32(afr.v, v1, o1);
          }
        }

        if (kt == 7) break;
        asm volatile("s_barrier" ::: "memory");
        if (kt < 6) {
          stageKV(kt + 2, p);
          asm volatile("s_waitcnt vmcnt(2)" ::: "memory");
        } else {
          asm volatile("s_waitcnt vmcnt(0)" ::: "memory");
        }
        asm volatile("s_barrier" ::: "memory");
      }

      psum += __shfl_xor(psum, 32);
      float inv = 1.f / psum;
#pragma unroll
      for (int r = 0; r < 16; ++r) {
        int q_r = (r & 3) + 8 * (r >> 2) + 4 * hl;
        float sc = __shfl(inv, q_r);
        size_t grow = (size_t)(bp * 512 + t0 + wid * 32 + q_r);
        ao[grow * 1024 + head * 64 + lo32]      = f2bf(o0[r] * sc);
        ao[grow * 1024 + head * 64 + 32 + lo32] = f2bf(o1[r] * sc);
      }
    }
  }
  grid.sync();

  // ================= stage D: 128x256xK=1024 O GEMM (256 tiles) ============
  {
    constexpr int K = 1024;
    constexpr int KT = K / 64;
    unsigned short* SmD = (unsigned short*)LDSb;           // [2][(128+256)*64]
    const unsigned short* Ain = xb;                        // attn output

    int lane = tid & 63, wid = tid >> 6;
    int quad = lane >> 4, lo = lane & 15;
    int wg = (bid & 7) * 32 + (bid >> 3);                  // T1: 256 = 8 x 32
    int tn = wg & 3, tm = wg >> 2;
    int wr = wid >> 2, wc = wid & 3;
    int srow = lane >> 3, schunk = lane & 7;
    int cg_ = schunk ^ srow;

    const unsigned short* pa = Ain + ((size_t)(tm * 128) + wid * 8 + srow) * K + cg_ * 8;
    const unsigned short* pb = wot + ((size_t)(tn * 256) + wid * 8 + srow) * K + cg_ * 8;

    f32x4 z = {0.f, 0.f, 0.f, 0.f};
    f32x4 acc[4][4];
#pragma unroll
    for (int i = 0; i < 4; ++i)
#pragma unroll
      for (int j = 0; j < 4; ++j) acc[i][j] = z;

    auto stage = [&](int t, int p) {
      unsigned short* As = SmD + (size_t)p * 24576;
      unsigned short* Bs = As + 128 * 64;
#pragma unroll
      for (int i = 0; i < 2; ++i)
        ld_lds16(pa + (size_t)i * 64 * K + t * 64,
                 (char*)As + (wid * 8 + i * 64) * 128);
#pragma unroll
      for (int i = 0; i < 4; ++i)
        ld_lds16(pb + (size_t)i * 64 * K + t * 64,
                 (char*)Bs + (wid * 8 + i * 64) * 128);
    };

    stage(0, 0);
    stage(1, 1);
    asm volatile("s_waitcnt vmcnt(6)" ::: "memory");
    asm volatile("s_barrier" ::: "memory");

    bf16x8 af[4][2], bb0[2][2], bb1[2][2];

    for (int t = 0; t < KT; ++t) {
      int p = t & 1;
      const unsigned short* As = SmD + (size_t)p * 24576;
      const unsigned short* Bs = As + 128 * 64;

      // P1: af + bb half0; MFMA (n0,n1)
#pragma unroll
      for (int mi = 0; mi < 4; ++mi)
#pragma unroll
        for (int kx = 0; kx < 2; ++kx) {
          int row = wr * 64 + mi * 16 + lo;
          int cgx = (quad + kx * 4) ^ (row & 7);
          af[mi][kx] = *(const bf16x8*)(As + (size_t)row * 64 + cgx * 8);
        }
#pragma unroll
      for (int ni = 0; ni < 2; ++ni)
#pragma unroll
        for (int kx = 0; kx < 2; ++kx) {
          int row = wc * 64 + ni * 16 + lo;
          int cgx = (quad + kx * 4) ^ (row & 7);
          bb0[ni][kx] = *(const bf16x8*)(Bs + (size_t)row * 64 + cgx * 8);
        }
      asm volatile("s_barrier" ::: "memory");
      __builtin_amdgcn_s_setprio(1);
#pragma unroll
      for (int kx = 0; kx < 2; ++kx)
#pragma unroll
        for (int mi = 0; mi < 4; ++mi)
#pragma unroll
          for (int ni = 0; ni < 2; ++ni)
            acc[mi][ni] = mfma16(af[mi][kx], bb0[ni][kx], acc[mi][ni]);
      __builtin_amdgcn_s_setprio(0);
      asm volatile("s_barrier" ::: "memory");

      // P2: bb half1; MFMA (n2,n3)
#pragma unroll
      for (int ni = 0; ni < 2; ++ni)
#pragma unroll
        for (int kx = 0; kx < 2; ++kx) {
          int row = wc * 64 + (ni + 2) * 16 + lo;
          int cgx = (quad + kx * 4) ^ (row & 7);
          bb1[ni][kx] = *(const bf16x8*)(Bs + (size_t)row * 64 + cgx * 8);
        }
      asm volatile("s_barrier" ::: "memory");
      __builtin_amdgcn_s_setprio(1);
#pragma unroll
      for (int kx = 0; kx < 2; ++kx)
#pragma unroll
        for (int mi = 0; mi < 4; ++mi)
#pragma unroll
          for (int ni = 0; ni < 2; ++ni)
            acc[mi][ni + 2] = mfma16(af[mi][kx], bb1[ni][kx], acc[mi][ni + 2]);
      __builtin_amdgcn_s_setprio(0);
      asm volatile("s_barrier" ::: "memory");

      // P3: prefetch t+2; counted vmcnt
      bool pf = (t + 2 < KT);
      if (pf) {
        stage(t + 2, p);
        asm volatile("s_waitcnt vmcnt(6)" ::: "memory");
      } else {
        asm volatile("s_waitcnt vmcnt(0)" ::: "memory");
      }
      asm volatile("s_barrier" ::: "memory");
    }

    // epilogue: fp32 out[(b,t,p),col]
#pragma unroll
    for (int mi = 0; mi < 4; ++mi) {
      for (int ni = 0; ni < 4; ++ni) {
        int col = tn * 256 + wc * 64 + ni * 16 + lo;
        for (int r = 0; r < 4; ++r) {
          int grow = tm * 128 + wr * 64 + mi * 16 + quad * 4 + r;
          int bp = grow >> 9, tt = grow & 511;
          int b = bp >> 3, pp = bp & 7;
          out[((((size_t)b * 512 + tt) * 8 + pp) << 10) + col] = acc[mi][ni][r];
        }
      }
    }
  }
}

extern "C" void kernel_launch(void* const* d_in, const int* in_sizes, int n_in,
                              void* d_out, int out_size, void* d_ws, size_t ws_size,
                              hipStream_t stream) {
  const float* hs = (const float*)d_in[0];
  const float* Wq = (const float*)d_in[1];
  const float* Wk = (const float*)d_in[2];
  const float* Wv = (const float*)d_in[3];
  const float* Wo = (const float*)d_in[4];
  float* out = (float*)d_out;

  unsigned short* xb   = (unsigned short*)d_ws;                 // 8192*1024
  unsigned short* wqkv = xb + (size_t)8192 * 1024;              // 1536*1024
  unsigned short* wot  = wqkv + (size_t)1536 * 1024;            // 1024*1024
  unsigned short* qbuf = wot + (size_t)1024 * 1024;             // 8192*1024
  unsigned short* kbuf = qbuf + (size_t)8192 * 1024;            // 8192*256
  unsigned short* vtb  = kbuf + (size_t)8192 * 256;             // 8192*256

  void* ka[12] = {(void*)&hs, (void*)&Wq, (void*)&Wk, (void*)&Wv, (void*)&Wo,
                  (void*)&xb, (void*)&wqkv, (void*)&wot, (void*)&qbuf,
                  (void*)&kbuf, (void*)&vtb, (void*)&out};
  hipLaunchCooperativeKernel((const void*)mega, dim3(256), dim3(512), ka, 0, stream);
}

// Round 6
// 179.509 us; speedup vs baseline: 1.6306x; 1.6306x over previous
//
#include <hip/hip_runtime.h>
#include <stdint.h>

// Problem constants: B=2, T=512, P=8, D=1024, NH=16, NKV=4, HD=64
// Rows (b,p,t): 16*512 = 8192.

typedef __attribute__((ext_vector_type(8))) short bf16x8;
typedef __attribute__((ext_vector_type(4))) float f32x4;
typedef __attribute__((ext_vector_type(16))) float f32x16;
typedef __attribute__((ext_vector_type(4))) unsigned short us4;
typedef __attribute__((ext_vector_type(8))) unsigned short us8;

static __device__ __forceinline__ unsigned short f2bf(float f) {
  unsigned u = __float_as_uint(f);
  u += 0x7fffu + ((u >> 16) & 1u);   // RNE
  return (unsigned short)(u >> 16);
}

static __device__ __forceinline__ void ld_lds16(const void* g, void* l) {
  __builtin_amdgcn_global_load_lds(
      (const __attribute__((address_space(1))) void*)g,
      (__attribute__((address_space(3))) void*)l, 16, 0, 0);
}

static __device__ __forceinline__ f32x4 mfma16(bf16x8 a, bf16x8 b, f32x4 c) {
  return __builtin_amdgcn_mfma_f32_16x16x32_bf16(a, b, c, 0, 0, 0);
}
static __device__ __forceinline__ f32x16 mfma32(bf16x8 a, bf16x8 b, f32x16 c) {
  return __builtin_amdgcn_mfma_f32_32x32x16_bf16(a, b, c, 0, 0, 0);
}

// ---- fused conversions: blocks 0..8191 pack x; 8192..8831 transpose W ----
__global__ __launch_bounds__(256) void conv_all(
    const float* __restrict__ hs, const float* __restrict__ Wq,
    const float* __restrict__ Wk, const float* __restrict__ Wv,
    const float* __restrict__ Wo, unsigned short* __restrict__ xb,
    unsigned short* __restrict__ wqkv, unsigned short* __restrict__ wot) {
  __shared__ float tile[64][65];
  int bid = blockIdx.x, tid = threadIdx.x;
  if (bid < 8192) {
    int gid = bid * 256 + tid;
    size_t e = (size_t)gid * 4;
    int r = (int)(e >> 10);          // bp*512 + t
    int d = (int)(e & 1023);
    int b = r >> 12, p = (r >> 9) & 7, t = r & 511;
    const float4* src = (const float4*)(hs + ((((size_t)b * 512 + t) * 8 + p) << 10) + d);
    float4 v = *src;
    us4 o;
    o.x = f2bf(v.x); o.y = f2bf(v.y); o.z = f2bf(v.z); o.w = f2bf(v.w);
    *(us4*)(xb + e) = o;
    return;
  }
  int tb = bid - 8192;
  const float* W; unsigned short* Wt; int N, tc0, tn0;
  if (tb < 256)      { W = Wq; Wt = wqkv;                       N = 1024; tc0 = (tb >> 4) * 64;          tn0 = (tb & 15) * 64; }
  else if (tb < 320) { W = Wk; Wt = wqkv + (size_t)1024 * 1024; N = 256;  tc0 = ((tb - 256) >> 2) * 64;  tn0 = ((tb - 256) & 3) * 64; }
  else if (tb < 384) { W = Wv; Wt = wqkv + (size_t)1280 * 1024; N = 256;  tc0 = ((tb - 320) >> 2) * 64;  tn0 = ((tb - 320) & 3) * 64; }
  else               { W = Wo; Wt = wot;                        N = 1024; tc0 = ((tb - 384) >> 4) * 64;  tn0 = ((tb - 384) & 15) * 64; }
  int tr = tid >> 4, tc = tid & 15;
#pragma unroll
  for (int i = 0; i < 4; ++i) {
    int c = tr + i * 16;
    float4 v = *(const float4*)(W + (size_t)(tc0 + c) * N + tn0 + tc * 4);
    tile[c][tc * 4 + 0] = v.x; tile[c][tc * 4 + 1] = v.y;
    tile[c][tc * 4 + 2] = v.z; tile[c][tc * 4 + 3] = v.w;
  }
  __syncthreads();
#pragma unroll
  for (int i = 0; i < 4; ++i) {
    int n = tr + i * 16;
    us4 o;
    o.x = f2bf(tile[tc * 4 + 0][n]); o.y = f2bf(tile[tc * 4 + 1][n]);
    o.z = f2bf(tile[tc * 4 + 2][n]); o.w = f2bf(tile[tc * 4 + 3][n]);
    *(us4*)(Wt + (size_t)(tn0 + n) * 1024 + tc0 + tc * 4) = o;
  }
}

// ---- 256x256x(K=1024) bf16 QKV GEMM, 8-phase schedule (r3-verified) -----
__global__ __launch_bounds__(512, 2) void gemm_qkv(
    const unsigned short* __restrict__ A, const unsigned short* __restrict__ Bt,
    unsigned short* __restrict__ qb, unsigned short* __restrict__ kb,
    unsigned short* __restrict__ vtb) {
  constexpr int K = 1024;
  constexpr int KT = K / 64;                       // 16 K-tiles
  __shared__ __align__(16) unsigned short Sm[2][2][256 * 64];  // [buf][A|B]
  unsigned short* Cs = &Sm[0][0][0];               // epilogue reuse, 128 KiB

  int tid = threadIdx.x;
  int lane = tid & 63, wid = tid >> 6;
  int quad = lane >> 4, lo = lane & 15;
  int wg = (blockIdx.x & 7) * 24 + (blockIdx.x >> 3);   // T1: 192 = 8 x 24
  int tn = wg % 6, tm = wg / 6;
  int wr = wid >> 2, wc = wid & 3;
  int srow = lane >> 3, schunk = lane & 7;
  int cg = schunk ^ srow;

  const unsigned short* pa = A + ((size_t)(tm * 256) + wid * 8 + srow) * K + cg * 8;
  const unsigned short* pb = Bt + ((size_t)(tn * 256) + wid * 8 + srow) * K + cg * 8;

  f32x4 z = {0.f, 0.f, 0.f, 0.f};
  f32x4 acc[8][4];
#pragma unroll
  for (int i = 0; i < 8; ++i)
#pragma unroll
    for (int j = 0; j < 4; ++j) acc[i][j] = z;

  auto stage = [&](int t, int p) {
#pragma unroll
    for (int i = 0; i < 4; ++i) {
      ld_lds16(pa + (size_t)i * 64 * K + t * 64,
               (char*)&Sm[p][0][0] + (wid * 8 + i * 64) * 128);
      ld_lds16(pb + (size_t)i * 64 * K + t * 64,
               (char*)&Sm[p][1][0] + (wid * 8 + i * 64) * 128);
    }
  };

  stage(0, 0);
  stage(1, 1);
  asm volatile("s_waitcnt vmcnt(8)" ::: "memory");   // tile 0 landed
  asm volatile("s_barrier" ::: "memory");

  bf16x8 af[4][2], bb0[2][2], bb1[2][2];

  for (int t = 0; t < KT; ++t) {
    int p = t & 1;
    const unsigned short* As = &Sm[p][0][0];
    const unsigned short* Bs = &Sm[p][1][0];

    // P1: af half0 + bb half0; MFMA (m0,n0)
#pragma unroll
    for (int mi = 0; mi < 4; ++mi)
#pragma unroll
      for (int kx = 0; kx < 2; ++kx) {
        int row = wr * 128 + mi * 16 + lo;
        int cgx = (quad + kx * 4) ^ (row & 7);
        af[mi][kx] = *(const bf16x8*)(As + (size_t)row * 64 + cgx * 8);
      }
#pragma unroll
    for (int ni = 0; ni < 2; ++ni)
#pragma unroll
      for (int kx = 0; kx < 2; ++kx) {
        int row = wc * 64 + ni * 16 + lo;
        int cgx = (quad + kx * 4) ^ (row & 7);
        bb0[ni][kx] = *(const bf16x8*)(Bs + (size_t)row * 64 + cgx * 8);
      }
    asm volatile("s_barrier" ::: "memory");
    __builtin_amdgcn_s_setprio(1);
#pragma unroll
    for (int kx = 0; kx < 2; ++kx)
#pragma unroll
      for (int mi = 0; mi < 4; ++mi)
#pragma unroll
        for (int ni = 0; ni < 2; ++ni)
          acc[mi][ni] = mfma16(af[mi][kx], bb0[ni][kx], acc[mi][ni]);
    __builtin_amdgcn_s_setprio(0);
    asm volatile("s_barrier" ::: "memory");

    // P2: bb half1; MFMA (m0,n1)
#pragma unroll
    for (int ni = 0; ni < 2; ++ni)
#pragma unroll
      for (int kx = 0; kx < 2; ++kx) {
        int row = wc * 64 + (ni + 2) * 16 + lo;
        int cgx = (quad + kx * 4) ^ (row & 7);
        bb1[ni][kx] = *(const bf16x8*)(Bs + (size_t)row * 64 + cgx * 8);
      }
    asm volatile("s_barrier" ::: "memory");
    __builtin_amdgcn_s_setprio(1);
#pragma unroll
    for (int kx = 0; kx < 2; ++kx)
#pragma unroll
      for (int mi = 0; mi < 4; ++mi)
#pragma unroll
        for (int ni = 0; ni < 2; ++ni)
          acc[mi][ni + 2] = mfma16(af[mi][kx], bb1[ni][kx], acc[mi][ni + 2]);
    __builtin_amdgcn_s_setprio(0);
    asm volatile("s_barrier" ::: "memory");

    // P3: af half1 (overwrite); MFMA (m1,n1)
#pragma unroll
    for (int mi = 0; mi < 4; ++mi)
#pragma unroll
      for (int kx = 0; kx < 2; ++kx) {
        int row = wr * 128 + 64 + mi * 16 + lo;
        int cgx = (quad + kx * 4) ^ (row & 7);
        af[mi][kx] = *(const bf16x8*)(As + (size_t)row * 64 + cgx * 8);
      }
    asm volatile("s_barrier" ::: "memory");
    __builtin_amdgcn_s_setprio(1);
#pragma unroll
    for (int kx = 0; kx < 2; ++kx)
#pragma unroll
      for (int mi = 0; mi < 4; ++mi)
#pragma unroll
        for (int ni = 0; ni < 2; ++ni)
          acc[mi + 4][ni + 2] = mfma16(af[mi][kx], bb1[ni][kx], acc[mi + 4][ni + 2]);
    __builtin_amdgcn_s_setprio(0);
    asm volatile("s_barrier" ::: "memory");

    // P4: prefetch t+2; MFMA (m1,n0); counted vmcnt
    bool pf = (t + 2 < KT);
    if (pf) stage(t + 2, p);
    __builtin_amdgcn_s_setprio(1);
#pragma unroll
    for (int kx = 0; kx < 2; ++kx)
#pragma unroll
      for (int mi = 0; mi < 4; ++mi)
#pragma unroll
        for (int ni = 0; ni < 2; ++ni)
          acc[mi + 4][ni] = mfma16(af[mi][kx], bb0[ni][kx], acc[mi + 4][ni]);
    __builtin_amdgcn_s_setprio(0);
    if (pf) asm volatile("s_waitcnt vmcnt(8)" ::: "memory");
    else    asm volatile("s_waitcnt vmcnt(0)" ::: "memory");
    asm volatile("s_barrier" ::: "memory");
  }

  // epilogue: C/D frag layout col = lane&15, row = quad*4 + r
  if (tn < 5) {
    float qscale = (tn < 4) ? 0.125f : 1.0f;       // fold 1/sqrt(HD) into Q
#pragma unroll
    for (int mi = 0; mi < 8; ++mi)
#pragma unroll
      for (int r = 0; r < 4; ++r) {
        int row = wr * 128 + mi * 16 + quad * 4 + r;
        int tpos = (tm * 256 + row) & 511;
#pragma unroll
        for (int ni = 0; ni < 2; ++ni) {
          float invf = exp2f((float)(ni * 16 + lo) * -0.41524101186092029f);
          float ang = (float)tpos * invf;
          float s, c;
          __sincosf(ang, &s, &c);
          float x1 = acc[mi][ni][r], x2 = acc[mi][ni + 2][r];
          acc[mi][ni][r]     = (x1 * c - x2 * s) * qscale;
          acc[mi][ni + 2][r] = (x1 * s + x2 * c) * qscale;
        }
      }
#pragma unroll
    for (int mi = 0; mi < 8; ++mi)
#pragma unroll
      for (int ni = 0; ni < 4; ++ni)
#pragma unroll
        for (int r = 0; r < 4; ++r) {
          int row = wr * 128 + mi * 16 + quad * 4 + r;
          int col = wc * 64 + ni * 16 + lo;
          int cs = col ^ (((row >> 2) & 3) << 3);
          Cs[row * 256 + cs] = f2bf(acc[mi][ni][r]);
        }
    __syncthreads();
    int tc = tid & 31, ro = tid >> 5;
#pragma unroll
    for (int it = 0; it < 16; ++it) {
      int row = ro + 16 * it;
      int cs = (tc * 8) ^ (((row >> 2) & 3) << 3);
      us8 v = *(const us8*)(Cs + row * 256 + cs);
      size_t grow = (size_t)(tm * 256 + row);
      if (tn < 4) *(us8*)(qb + grow * 1024 + tn * 256 + tc * 8) = v;
      else        *(us8*)(kb + grow * 256 + tc * 8) = v;
    }
  } else {
    // V^T: stage transposed into Cs[col][t-local], then coalesced stores.
#pragma unroll
    for (int mi = 0; mi < 8; ++mi)
#pragma unroll
      for (int ni = 0; ni < 4; ++ni)
#pragma unroll
        for (int r = 0; r < 4; ++r) {
          int trow = wr * 128 + mi * 16 + quad * 4 + r;   // t-local 0..255
          int col = wc * 64 + ni * 16 + lo;               // c-local 0..255
          Cs[col * 256 + (trow ^ ((col & 7) << 3))] = f2bf(acc[mi][ni][r]);
        }
    __syncthreads();
    int t0 = (tid & 31) * 8, colIdx = tid >> 5;
    int bp = tm >> 1, tbase = (tm & 1) * 256;
#pragma unroll
    for (int it = 0; it < 16; ++it) {
      int col = colIdx + it * 16;
      us8 v = *(const us8*)(Cs + col * 256 + (t0 ^ ((col & 7) << 3)));
      int hh = col >> 6, dd = col & 63;
      *(us8*)(vtb + (((size_t)(bp * 4 + hh)) * 64 + dd) * 512 + tbase + t0) = v;
    }
  }
}

// ---- 128x256x(K=1024) O-proj GEMM: 256 blocks = 100% grid fill ----------
__global__ __launch_bounds__(512, 2) void gemm_o(
    const unsigned short* __restrict__ A, const unsigned short* __restrict__ Bt,
    float* __restrict__ out) {
  constexpr int K = 1024;
  constexpr int KT = K / 64;
  __shared__ __align__(16) unsigned short Sm[2][(128 + 256) * 64];

  int tid = threadIdx.x;
  int lane = tid & 63, wid = tid >> 6;
  int quad = lane >> 4, lo = lane & 15;
  int wg = (blockIdx.x & 7) * 32 + (blockIdx.x >> 3);   // T1: 256 = 8 x 32
  int tn = wg & 3, tm = wg >> 2;                        // tm 0..63, tn 0..3
  int wr = wid >> 2, wc = wid & 3;
  int srow = lane >> 3, schunk = lane & 7;
  int cg = schunk ^ srow;

  const unsigned short* pa = A + ((size_t)(tm * 128) + wid * 8 + srow) * K + cg * 8;
  const unsigned short* pb = Bt + ((size_t)(tn * 256) + wid * 8 + srow) * K + cg * 8;

  f32x4 z = {0.f, 0.f, 0.f, 0.f};
  f32x4 acc[4][4];
#pragma unroll
  for (int i = 0; i < 4; ++i)
#pragma unroll
    for (int j = 0; j < 4; ++j) acc[i][j] = z;

  auto stage = [&](int t, int p) {
    unsigned short* As = &Sm[p][0];
    unsigned short* Bs = &Sm[p][128 * 64];
#pragma unroll
    for (int i = 0; i < 2; ++i)
      ld_lds16(pa + (size_t)i * 64 * K + t * 64,
               (char*)As + (wid * 8 + i * 64) * 128);
#pragma unroll
    for (int i = 0; i < 4; ++i)
      ld_lds16(pb + (size_t)i * 64 * K + t * 64,
               (char*)Bs + (wid * 8 + i * 64) * 128);
  };

  stage(0, 0);
  stage(1, 1);
  asm volatile("s_waitcnt vmcnt(6)" ::: "memory");   // tile 0 landed
  asm volatile("s_barrier" ::: "memory");

  bf16x8 af[4][2], bb0[2][2], bb1[2][2];

  for (int t = 0; t < KT; ++t) {
    int p = t & 1;
    const unsigned short* As = &Sm[p][0];
    const unsigned short* Bs = &Sm[p][128 * 64];

    // P1: af + bb half0; MFMA (n0,n1)
#pragma unroll
    for (int mi = 0; mi < 4; ++mi)
#pragma unroll
      for (int kx = 0; kx < 2; ++kx) {
        int row = wr * 64 + mi * 16 + lo;
        int cgx = (quad + kx * 4) ^ (row & 7);
        af[mi][kx] = *(const bf16x8*)(As + (size_t)row * 64 + cgx * 8);
      }
#pragma unroll
    for (int ni = 0; ni < 2; ++ni)
#pragma unroll
      for (int kx = 0; kx < 2; ++kx) {
        int row = wc * 64 + ni * 16 + lo;
        int cgx = (quad + kx * 4) ^ (row & 7);
        bb0[ni][kx] = *(const bf16x8*)(Bs + (size_t)row * 64 + cgx * 8);
      }
    asm volatile("s_barrier" ::: "memory");
    __builtin_amdgcn_s_setprio(1);
#pragma unroll
    for (int kx = 0; kx < 2; ++kx)
#pragma unroll
      for (int mi = 0; mi < 4; ++mi)
#pragma unroll
        for (int ni = 0; ni < 2; ++ni)
          acc[mi][ni] = mfma16(af[mi][kx], bb0[ni][kx], acc[mi][ni]);
    __builtin_amdgcn_s_setprio(0);
    asm volatile("s_barrier" ::: "memory");

    // P2: bb half1; MFMA (n2,n3)
#pragma unroll
    for (int ni = 0; ni < 2; ++ni)
#pragma unroll
      for (int kx = 0; kx < 2; ++kx) {
        int row = wc * 64 + (ni + 2) * 16 + lo;
        int cgx = (quad + kx * 4) ^ (row & 7);
        bb1[ni][kx] = *(const bf16x8*)(Bs + (size_t)row * 64 + cgx * 8);
      }
    asm volatile("s_barrier" ::: "memory");
    __builtin_amdgcn_s_setprio(1);
#pragma unroll
    for (int kx = 0; kx < 2; ++kx)
#pragma unroll
      for (int mi = 0; mi < 4; ++mi)
#pragma unroll
        for (int ni = 0; ni < 2; ++ni)
          acc[mi][ni + 2] = mfma16(af[mi][kx], bb1[ni][kx], acc[mi][ni + 2]);
    __builtin_amdgcn_s_setprio(0);
    asm volatile("s_barrier" ::: "memory");

    // P3: prefetch t+2 (all tile-t reads drained); counted vmcnt
    bool pf = (t + 2 < KT);
    if (pf) {
      stage(t + 2, p);
      asm volatile("s_waitcnt vmcnt(6)" ::: "memory");
    } else {
      asm volatile("s_waitcnt vmcnt(0)" ::: "memory");
    }
    asm volatile("s_barrier" ::: "memory");
  }

  // epilogue: fp32 out[(b,t,p),col]
#pragma unroll
  for (int mi = 0; mi < 4; ++mi) {
    for (int ni = 0; ni < 4; ++ni) {
      int col = tn * 256 + wc * 64 + ni * 16 + lo;
      for (int r = 0; r < 4; ++r) {
        int grow = tm * 128 + wr * 64 + mi * 16 + quad * 4 + r;
        int bp = grow >> 9, tt = grow & 511;
        int b = bp >> 3, pp = bp & 7;
        out[((((size_t)b * 512 + tt) * 8 + pp) << 10) + col] = acc[mi][ni][r];
      }
    }
  }
}

// ---- attention v3: LDS-BW-optimized ------------------------------------
// r5 diagnosis: attn is LDS-read-bandwidth bound (per-CU LDS ~85 B/cyc vs
// 4 SIMDs consuming fragments at ~512 B/cyc when reads:MFMA = 1:1), so r4's
// latency fixes were null. This version raises MFMA-per-LDS-byte 2.5x:
//   - Q in REGISTERS (8 bf16x8/lane, loaded once from global): -4 reads/kt
//   - each wave owns 64 q-rows (2 column-sets A,B): every K and V fragment
//     read feeds 2 MFMAs. Per kt: 16 ds_read_b128 -> 32 mfma32 (was 20->16).
// Block = 512 thr = 8 waves = 512 q-rows = one (bp,head); grid 256 = 16x16,
// 1 block/CU. LDS = K/V dbuf only (32 KiB). Counted-vmcnt staging kept.
__global__ __launch_bounds__(512, 2) void attn(
    const unsigned short* __restrict__ qbuf, const unsigned short* __restrict__ kb,
    const unsigned short* __restrict__ vtb, unsigned short* __restrict__ ao) {
  __shared__ __align__(16) unsigned short Ks[2][64 * 64];
  __shared__ __align__(16) unsigned short Vs[2][64 * 64];  // V^T: [d][key]

  int tid = threadIdx.x;
  int lane = tid & 63, wid = tid >> 6;                  // wid 0..7
  int lo32 = lane & 31, hl = lane >> 5;
  int wg = (blockIdx.x & 7) * 32 + (blockIdx.x >> 3);   // T1: 256 = 8 x 32
  int head = wg & 15, bp = wg >> 4;
  int kvh = head >> 2;
  int srow = lane >> 3, schunk = lane & 7;

  const unsigned short* kg = kb + ((size_t)bp * 512) * 256 + kvh * 64;
  const unsigned short* vg = vtb + ((size_t)(bp * 4 + kvh)) * 64 * 512;

  // Q to registers: set A rows wid*64+lo32, set B rows +32. 8 x us8 loads;
  // the two hl-halves together consume each 128B row-line fully.
  const unsigned short* qgA =
      qbuf + ((size_t)(bp * 512 + wid * 64 + lo32)) * 1024 + head * 64;
  bf16x8 qA[4], qB[4];
#pragma unroll
  for (int kkc = 0; kkc < 4; ++kkc) {
    int ch = 2 * kkc + hl;
    qA[kkc] = *(const bf16x8*)(qgA + ch * 8);
    qB[kkc] = *(const bf16x8*)(qgA + (size_t)32 * 1024 + ch * 8);
  }

  auto stageKV = [&](int kt, int p) {   // 64 keys of K and V^T
    int row = wid * 8 + srow;
    int cg = schunk ^ (row & 7);
    ld_lds16(kg + (size_t)(kt * 64 + row) * 256 + cg * 8,
             (char*)&Ks[p][0] + (wid * 8) * 128);
    ld_lds16(vg + (size_t)row * 512 + kt * 64 + cg * 8,
             (char*)&Vs[p][0] + (wid * 8) * 128);
  };

  stageKV(0, 0);                   // outstanding: Q(8) + 2
  stageKV(1, 1);                   // + 2 = 12
  asm volatile("s_waitcnt vmcnt(2)" ::: "memory");   // Q + tile0 landed
  asm volatile("s_barrier" ::: "memory");

  f32x16 z16 = {0.f};
  f32x16 oA0 = z16, oA1 = z16, oB0 = z16, oB1 = z16;
  float psumA = 0.f, psumB = 0.f;

  for (int kt = 0; kt < 8; ++kt) {
    int p = kt & 1;
    const unsigned short* Kp = &Ks[p][0];
    const unsigned short* Vp = &Vs[p][0];

    // S^T = K . Q^T over d=64; each kf feeds BOTH q-sets.
    f32x16 sA0 = z16, sA1 = z16, sB0 = z16, sB1 = z16;
#pragma unroll
    for (int kkc = 0; kkc < 4; ++kkc) {
      int ch = 2 * kkc + hl;
      bf16x8 kf0 = *(const bf16x8*)(Kp + (size_t)lo32 * 64 + ((ch ^ (lo32 & 7)) * 8));
      bf16x8 kf1 = *(const bf16x8*)(Kp + (size_t)(32 + lo32) * 64 + ((ch ^ (lo32 & 7)) * 8));
      sA0 = mfma32(kf0, qA[kkc], sA0);
      sA1 = mfma32(kf1, qA[kkc], sA1);
      sB0 = mfma32(kf0, qB[kkc], sB0);
      sB1 = mfma32(kf1, qB[kkc], sB1);
    }

    // exp (scale pre-folded into Q), pack, PV; each v-frag feeds both sets.
#pragma unroll
    for (int t = 0; t < 2; ++t) {
      const f32x16& svA = t ? sA1 : sA0;
      const f32x16& svB = t ? sB1 : sB0;
      unsigned pkA[8], xpA[8], pkB[8], xpB[8];
#pragma unroll
      for (int pp = 0; pp < 8; ++pp) {
        float a0 = __expf(svA[2 * pp]);
        float a1 = __expf(svA[2 * pp + 1]);
        psumA += a0 + a1;
        pkA[pp] = ((__float_as_uint(a0) + 0x8000u) >> 16) |
                  ((__float_as_uint(a1) + 0x8000u) & 0xffff0000u);
        float b0 = __expf(svB[2 * pp]);
        float b1 = __expf(svB[2 * pp + 1]);
        psumB += b0 + b1;
        pkB[pp] = ((__float_as_uint(b0) + 0x8000u) >> 16) |
                  ((__float_as_uint(b1) + 0x8000u) & 0xffff0000u);
      }
#pragma unroll
      for (int pp = 0; pp < 8; ++pp) {
        xpA[pp] = (unsigned)__shfl_xor((int)pkA[pp], 32);
        xpB[pp] = (unsigned)__shfl_xor((int)pkB[pp], 32);
      }
#pragma unroll
      for (int cc = 0; cc < 2; ++cc) {
        int o = cc * 4;
        union { unsigned u[4]; bf16x8 v; } fA, fB;
        if (hl == 0) {
          fA.u[0] = pkA[o];     fA.u[1] = pkA[o + 1];
          fA.u[2] = xpA[o];     fA.u[3] = xpA[o + 1];
          fB.u[0] = pkB[o];     fB.u[1] = pkB[o + 1];
          fB.u[2] = xpB[o];     fB.u[3] = xpB[o + 1];
        } else {
          fA.u[0] = xpA[o + 2]; fA.u[1] = xpA[o + 3];
          fA.u[2] = pkA[o + 2]; fA.u[3] = pkA[o + 3];
          fB.u[0] = xpB[o + 2]; fB.u[1] = xpB[o + 3];
          fB.u[2] = pkB[o + 2]; fB.u[3] = pkB[o + 3];
        }
        int vch = 2 * (t * 2 + cc) + hl;
        bf16x8 v0 = *(const bf16x8*)(Vp + (size_t)lo32 * 64 + ((vch ^ (lo32 & 7)) * 8));
        bf16x8 v1 = *(const bf16x8*)(Vp + (size_t)(32 + lo32) * 64 + ((vch ^ (lo32 & 7)) * 8));
        oA0 = mfma32(fA.v, v0, oA0);
        oA1 = mfma32(fA.v, v1, oA1);
        oB0 = mfma32(fB.v, v0, oB0);
        oB1 = mfma32(fB.v, v1, oB1);
      }
    }

    if (kt == 7) break;
    asm volatile("s_barrier" ::: "memory");            // done reading buf p
    if (kt < 6) {
      stageKV(kt + 2, p);                              // lands under tile kt+1
      asm volatile("s_waitcnt vmcnt(2)" ::: "memory"); // tile kt+1 landed
    } else {
      asm volatile("s_waitcnt vmcnt(0)" ::: "memory"); // tile 7 landed
    }
    asm volatile("s_barrier" ::: "memory");            // publish tile kt+1
  }

  // normalize and store: D layout col=lane&31=d, row q_r=(r&3)+8*(r>>2)+4*hl
  psumA += __shfl_xor(psumA, 32);
  psumB += __shfl_xor(psumB, 32);
  float invA = 1.f / psumA, invB = 1.f / psumB;
#pragma unroll
  for (int r = 0; r < 16; ++r) {
    int q_r = (r & 3) + 8 * (r >> 2) + 4 * hl;
    float scA = __shfl(invA, q_r);   // holder lane lo32=q_r
    float scB = __shfl(invB, q_r);
    size_t gA = (size_t)(bp * 512 + wid * 64 + q_r);
    ao[gA * 1024 + head * 64 + lo32]      = f2bf(oA0[r] * scA);
    ao[gA * 1024 + head * 64 + 32 + lo32] = f2bf(oA1[r] * scA);
    size_t gB = gA + 32;
    ao[gB * 1024 + head * 64 + lo32]      = f2bf(oB0[r] * scB);
    ao[gB * 1024 + head * 64 + 32 + lo32] = f2bf(oB1[r] * scB);
  }
}

extern "C" void kernel_launch(void* const* d_in, const int* in_sizes, int n_in,
                              void* d_out, int out_size, void* d_ws, size_t ws_size,
                              hipStream_t stream) {
  const float* hs = (const float*)d_in[0];
  const float* Wq = (const float*)d_in[1];
  const float* Wk = (const float*)d_in[2];
  const float* Wv = (const float*)d_in[3];
  const float* Wo = (const float*)d_in[4];
  float* out = (float*)d_out;

  unsigned short* xb   = (unsigned short*)d_ws;                 // 8192*1024
  unsigned short* wqkv = xb + (size_t)8192 * 1024;              // 1536*1024
  unsigned short* wot  = wqkv + (size_t)1536 * 1024;            // 1024*1024
  unsigned short* qbuf = wot + (size_t)1024 * 1024;             // 8192*1024
  unsigned short* kbuf = qbuf + (size_t)8192 * 1024;            // 8192*256
  unsigned short* vtb  = kbuf + (size_t)8192 * 256;             // 8192*256
  unsigned short* ao   = xb;                                    // alias

  conv_all<<<8832, 256, 0, stream>>>(hs, Wq, Wk, Wv, Wo, xb, wqkv, wot);
  gemm_qkv<<<192, 512, 0, stream>>>(xb, wqkv, qbuf, kbuf, vtb);
  attn<<<256, 512, 0, stream>>>(qbuf, kbuf, vtb, ao);
  gemm_o<<<256, 512, 0, stream>>>(ao, wot, out);
}

// Round 7
// 176.711 us; speedup vs baseline: 1.6564x; 1.0158x over previous
//
#include <hip/hip_runtime.h>
#include <stdint.h>

// Problem constants: B=2, T=512, P=8, D=1024, NH=16, NKV=4, HD=64
// Rows (b,p,t): 16*512 = 8192.

typedef __attribute__((ext_vector_type(8))) short bf16x8;
typedef __attribute__((ext_vector_type(4))) float f32x4;
typedef __attribute__((ext_vector_type(16))) float f32x16;
typedef __attribute__((ext_vector_type(4))) unsigned short us4;
typedef __attribute__((ext_vector_type(8))) unsigned short us8;

static __device__ __forceinline__ unsigned short f2bf(float f) {
  unsigned u = __float_as_uint(f);
  u += 0x7fffu + ((u >> 16) & 1u);   // RNE
  return (unsigned short)(u >> 16);
}

static __device__ __forceinline__ void ld_lds16(const void* g, void* l) {
  __builtin_amdgcn_global_load_lds(
      (const __attribute__((address_space(1))) void*)g,
      (__attribute__((address_space(3))) void*)l, 16, 0, 0);
}

static __device__ __forceinline__ f32x4 mfma16(bf16x8 a, bf16x8 b, f32x4 c) {
  return __builtin_amdgcn_mfma_f32_16x16x32_bf16(a, b, c, 0, 0, 0);
}
static __device__ __forceinline__ f32x16 mfma32(bf16x8 a, bf16x8 b, f32x16 c) {
  return __builtin_amdgcn_mfma_f32_32x32x16_bf16(a, b, c, 0, 0, 0);
}

// ---- fused conversions: blocks 0..8191 pack x; 8192..8831 transpose W ----
__global__ __launch_bounds__(256) void conv_all(
    const float* __restrict__ hs, const float* __restrict__ Wq,
    const float* __restrict__ Wk, const float* __restrict__ Wv,
    const float* __restrict__ Wo, unsigned short* __restrict__ xb,
    unsigned short* __restrict__ wqkv, unsigned short* __restrict__ wot) {
  __shared__ float tile[64][65];
  int bid = blockIdx.x, tid = threadIdx.x;
  if (bid < 8192) {
    int gid = bid * 256 + tid;
    size_t e = (size_t)gid * 4;
    int r = (int)(e >> 10);          // bp*512 + t
    int d = (int)(e & 1023);
    int b = r >> 12, p = (r >> 9) & 7, t = r & 511;
    const float4* src = (const float4*)(hs + ((((size_t)b * 512 + t) * 8 + p) << 10) + d);
    float4 v = *src;
    us4 o;
    o.x = f2bf(v.x); o.y = f2bf(v.y); o.z = f2bf(v.z); o.w = f2bf(v.w);
    *(us4*)(xb + e) = o;
    return;
  }
  int tb = bid - 8192;
  const float* W; unsigned short* Wt; int N, tc0, tn0;
  if (tb < 256)      { W = Wq; Wt = wqkv;                       N = 1024; tc0 = (tb >> 4) * 64;          tn0 = (tb & 15) * 64; }
  else if (tb < 320) { W = Wk; Wt = wqkv + (size_t)1024 * 1024; N = 256;  tc0 = ((tb - 256) >> 2) * 64;  tn0 = ((tb - 256) & 3) * 64; }
  else if (tb < 384) { W = Wv; Wt = wqkv + (size_t)1280 * 1024; N = 256;  tc0 = ((tb - 320) >> 2) * 64;  tn0 = ((tb - 320) & 3) * 64; }
  else               { W = Wo; Wt = wot;                        N = 1024; tc0 = ((tb - 384) >> 4) * 64;  tn0 = ((tb - 384) & 15) * 64; }
  int tr = tid >> 4, tc = tid & 15;
#pragma unroll
  for (int i = 0; i < 4; ++i) {
    int c = tr + i * 16;
    float4 v = *(const float4*)(W + (size_t)(tc0 + c) * N + tn0 + tc * 4);
    tile[c][tc * 4 + 0] = v.x; tile[c][tc * 4 + 1] = v.y;
    tile[c][tc * 4 + 2] = v.z; tile[c][tc * 4 + 3] = v.w;
  }
  __syncthreads();
#pragma unroll
  for (int i = 0; i < 4; ++i) {
    int n = tr + i * 16;
    us4 o;
    o.x = f2bf(tile[tc * 4 + 0][n]); o.y = f2bf(tile[tc * 4 + 1][n]);
    o.z = f2bf(tile[tc * 4 + 2][n]); o.w = f2bf(tile[tc * 4 + 3][n]);
    *(us4*)(Wt + (size_t)(tn0 + n) * 1024 + tc0 + tc * 4) = o;
  }
}

// ---- 256x256x(K=1024) bf16 QKV GEMM, 8-phase schedule (r3-verified) -----
__global__ __launch_bounds__(512, 2) void gemm_qkv(
    const unsigned short* __restrict__ A, const unsigned short* __restrict__ Bt,
    unsigned short* __restrict__ qb, unsigned short* __restrict__ kb,
    unsigned short* __restrict__ vtb) {
  constexpr int K = 1024;
  constexpr int KT = K / 64;                       // 16 K-tiles
  __shared__ __align__(16) unsigned short Sm[2][2][256 * 64];  // [buf][A|B]
  unsigned short* Cs = &Sm[0][0][0];               // epilogue reuse, 128 KiB

  int tid = threadIdx.x;
  int lane = tid & 63, wid = tid >> 6;
  int quad = lane >> 4, lo = lane & 15;
  int wg = (blockIdx.x & 7) * 24 + (blockIdx.x >> 3);   // T1: 192 = 8 x 24
  int tn = wg % 6, tm = wg / 6;
  int wr = wid >> 2, wc = wid & 3;
  int srow = lane >> 3, schunk = lane & 7;
  int cg = schunk ^ srow;

  const unsigned short* pa = A + ((size_t)(tm * 256) + wid * 8 + srow) * K + cg * 8;
  const unsigned short* pb = Bt + ((size_t)(tn * 256) + wid * 8 + srow) * K + cg * 8;

  f32x4 z = {0.f, 0.f, 0.f, 0.f};
  f32x4 acc[8][4];
#pragma unroll
  for (int i = 0; i < 8; ++i)
#pragma unroll
    for (int j = 0; j < 4; ++j) acc[i][j] = z;

  auto stage = [&](int t, int p) {
#pragma unroll
    for (int i = 0; i < 4; ++i) {
      ld_lds16(pa + (size_t)i * 64 * K + t * 64,
               (char*)&Sm[p][0][0] + (wid * 8 + i * 64) * 128);
      ld_lds16(pb + (size_t)i * 64 * K + t * 64,
               (char*)&Sm[p][1][0] + (wid * 8 + i * 64) * 128);
    }
  };

  stage(0, 0);
  stage(1, 1);
  asm volatile("s_waitcnt vmcnt(8)" ::: "memory");   // tile 0 landed
  asm volatile("s_barrier" ::: "memory");

  bf16x8 af[4][2], bb0[2][2], bb1[2][2];

  for (int t = 0; t < KT; ++t) {
    int p = t & 1;
    const unsigned short* As = &Sm[p][0][0];
    const unsigned short* Bs = &Sm[p][1][0];

    // P1: af half0 + bb half0; MFMA (m0,n0)
#pragma unroll
    for (int mi = 0; mi < 4; ++mi)
#pragma unroll
      for (int kx = 0; kx < 2; ++kx) {
        int row = wr * 128 + mi * 16 + lo;
        int cgx = (quad + kx * 4) ^ (row & 7);
        af[mi][kx] = *(const bf16x8*)(As + (size_t)row * 64 + cgx * 8);
      }
#pragma unroll
    for (int ni = 0; ni < 2; ++ni)
#pragma unroll
      for (int kx = 0; kx < 2; ++kx) {
        int row = wc * 64 + ni * 16 + lo;
        int cgx = (quad + kx * 4) ^ (row & 7);
        bb0[ni][kx] = *(const bf16x8*)(Bs + (size_t)row * 64 + cgx * 8);
      }
    asm volatile("s_barrier" ::: "memory");
    __builtin_amdgcn_s_setprio(1);
#pragma unroll
    for (int kx = 0; kx < 2; ++kx)
#pragma unroll
      for (int mi = 0; mi < 4; ++mi)
#pragma unroll
        for (int ni = 0; ni < 2; ++ni)
          acc[mi][ni] = mfma16(af[mi][kx], bb0[ni][kx], acc[mi][ni]);
    __builtin_amdgcn_s_setprio(0);
    asm volatile("s_barrier" ::: "memory");

    // P2: bb half1; MFMA (m0,n1)
#pragma unroll
    for (int ni = 0; ni < 2; ++ni)
#pragma unroll
      for (int kx = 0; kx < 2; ++kx) {
        int row = wc * 64 + (ni + 2) * 16 + lo;
        int cgx = (quad + kx * 4) ^ (row & 7);
        bb1[ni][kx] = *(const bf16x8*)(Bs + (size_t)row * 64 + cgx * 8);
      }
    asm volatile("s_barrier" ::: "memory");
    __builtin_amdgcn_s_setprio(1);
#pragma unroll
    for (int kx = 0; kx < 2; ++kx)
#pragma unroll
      for (int mi = 0; mi < 4; ++mi)
#pragma unroll
        for (int ni = 0; ni < 2; ++ni)
          acc[mi][ni + 2] = mfma16(af[mi][kx], bb1[ni][kx], acc[mi][ni + 2]);
    __builtin_amdgcn_s_setprio(0);
    asm volatile("s_barrier" ::: "memory");

    // P3: af half1 (overwrite); MFMA (m1,n1)
#pragma unroll
    for (int mi = 0; mi < 4; ++mi)
#pragma unroll
      for (int kx = 0; kx < 2; ++kx) {
        int row = wr * 128 + 64 + mi * 16 + lo;
        int cgx = (quad + kx * 4) ^ (row & 7);
        af[mi][kx] = *(const bf16x8*)(As + (size_t)row * 64 + cgx * 8);
      }
    asm volatile("s_barrier" ::: "memory");
    __builtin_amdgcn_s_setprio(1);
#pragma unroll
    for (int kx = 0; kx < 2; ++kx)
#pragma unroll
      for (int mi = 0; mi < 4; ++mi)
#pragma unroll
        for (int ni = 0; ni < 2; ++ni)
          acc[mi + 4][ni + 2] = mfma16(af[mi][kx], bb1[ni][kx], acc[mi + 4][ni + 2]);
    __builtin_amdgcn_s_setprio(0);
    asm volatile("s_barrier" ::: "memory");

    // P4: prefetch t+2; MFMA (m1,n0) from regs; counted vmcnt
    bool pf = (t + 2 < KT);
    if (pf) stage(t + 2, p);
    __builtin_amdgcn_s_setprio(1);
#pragma unroll
    for (int kx = 0; kx < 2; ++kx)
#pragma unroll
      for (int mi = 0; mi < 4; ++mi)
#pragma unroll
        for (int ni = 0; ni < 2; ++ni)
          acc[mi + 4][ni] = mfma16(af[mi][kx], bb0[ni][kx], acc[mi + 4][ni]);
    __builtin_amdgcn_s_setprio(0);
    if (pf) asm volatile("s_waitcnt vmcnt(8)" ::: "memory");
    else    asm volatile("s_waitcnt vmcnt(0)" ::: "memory");
    asm volatile("s_barrier" ::: "memory");
  }

  // epilogue: C/D frag layout col = lane&15, row = quad*4 + r
  if (tn < 5) {
    float qscale = (tn < 4) ? 0.125f : 1.0f;       // fold 1/sqrt(HD) into Q
#pragma unroll
    for (int mi = 0; mi < 8; ++mi)
#pragma unroll
      for (int r = 0; r < 4; ++r) {
        int row = wr * 128 + mi * 16 + quad * 4 + r;
        int tpos = (tm * 256 + row) & 511;
#pragma unroll
        for (int ni = 0; ni < 2; ++ni) {
          float invf = exp2f((float)(ni * 16 + lo) * -0.41524101186092029f);
          float ang = (float)tpos * invf;
          float s, c;
          __sincosf(ang, &s, &c);
          float x1 = acc[mi][ni][r], x2 = acc[mi][ni + 2][r];
          acc[mi][ni][r]     = (x1 * c - x2 * s) * qscale;
          acc[mi][ni + 2][r] = (x1 * s + x2 * c) * qscale;
        }
      }
#pragma unroll
    for (int mi = 0; mi < 8; ++mi)
#pragma unroll
      for (int ni = 0; ni < 4; ++ni)
#pragma unroll
        for (int r = 0; r < 4; ++r) {
          int row = wr * 128 + mi * 16 + quad * 4 + r;
          int col = wc * 64 + ni * 16 + lo;
          int cs = col ^ (((row >> 2) & 3) << 3);
          Cs[row * 256 + cs] = f2bf(acc[mi][ni][r]);
        }
    __syncthreads();
    int tc = tid & 31, ro = tid >> 5;
#pragma unroll
    for (int it = 0; it < 16; ++it) {
      int row = ro + 16 * it;
      int cs = (tc * 8) ^ (((row >> 2) & 3) << 3);
      us8 v = *(const us8*)(Cs + row * 256 + cs);
      size_t grow = (size_t)(tm * 256 + row);
      if (tn < 4) *(us8*)(qb + grow * 1024 + tn * 256 + tc * 8) = v;
      else        *(us8*)(kb + grow * 256 + tc * 8) = v;
    }
  } else {
    // V^T: stage transposed into Cs[col][t-local], then coalesced stores.
#pragma unroll
    for (int mi = 0; mi < 8; ++mi)
#pragma unroll
      for (int ni = 0; ni < 4; ++ni)
#pragma unroll
        for (int r = 0; r < 4; ++r) {
          int trow = wr * 128 + mi * 16 + quad * 4 + r;   // t-local 0..255
          int col = wc * 64 + ni * 16 + lo;               // c-local 0..255
          Cs[col * 256 + (trow ^ ((col & 7) << 3))] = f2bf(acc[mi][ni][r]);
        }
    __syncthreads();
    int t0 = (tid & 31) * 8, colIdx = tid >> 5;
    int bp = tm >> 1, tbase = (tm & 1) * 256;
#pragma unroll
    for (int it = 0; it < 16; ++it) {
      int col = colIdx + it * 16;
      us8 v = *(const us8*)(Cs + col * 256 + (t0 ^ ((col & 7) << 3)));
      int hh = col >> 6, dd = col & 63;
      *(us8*)(vtb + (((size_t)(bp * 4 + hh)) * 64 + dd) * 512 + tbase + t0) = v;
    }
  }
}

// ---- 128x256x(K=1024) O-proj GEMM, v2: no dead phase --------------------
// r6 post-mortem: old P3 was a pure prefetch/stall phase (2 barriers, 0
// MFMA). New split mirrors gemm_qkv's P4: P1 {ALL 16 ds_reads; bar; 16 MFMA
// (n0,n1); bar}, P2 {issue prefetch t+2; 16 MFMA (n2,n3) register-only;
// counted vmcnt(6); bar}. Barriers/K-tile 6 -> 4; prefetch hidden under
// MFMA. Race-safe: each wave's tile-t ds_reads complete (compiler waitcnt)
// before its P1 MFMA, which precedes the barrier P2's stage sits behind.
__global__ __launch_bounds__(512, 2) void gemm_o(
    const unsigned short* __restrict__ A, const unsigned short* __restrict__ Bt,
    float* __restrict__ out) {
  constexpr int K = 1024;
  constexpr int KT = K / 64;
  __shared__ __align__(16) unsigned short Sm[2][(128 + 256) * 64];

  int tid = threadIdx.x;
  int lane = tid & 63, wid = tid >> 6;
  int quad = lane >> 4, lo = lane & 15;
  int wg = (blockIdx.x & 7) * 32 + (blockIdx.x >> 3);   // T1: 256 = 8 x 32
  int tn = wg & 3, tm = wg >> 2;                        // tm 0..63, tn 0..3
  int wr = wid >> 2, wc = wid & 3;
  int srow = lane >> 3, schunk = lane & 7;
  int cg = schunk ^ srow;

  const unsigned short* pa = A + ((size_t)(tm * 128) + wid * 8 + srow) * K + cg * 8;
  const unsigned short* pb = Bt + ((size_t)(tn * 256) + wid * 8 + srow) * K + cg * 8;

  f32x4 z = {0.f, 0.f, 0.f, 0.f};
  f32x4 acc[4][4];
#pragma unroll
  for (int i = 0; i < 4; ++i)
#pragma unroll
    for (int j = 0; j < 4; ++j) acc[i][j] = z;

  auto stage = [&](int t, int p) {
    unsigned short* As = &Sm[p][0];
    unsigned short* Bs = &Sm[p][128 * 64];
#pragma unroll
    for (int i = 0; i < 2; ++i)
      ld_lds16(pa + (size_t)i * 64 * K + t * 64,
               (char*)As + (wid * 8 + i * 64) * 128);
#pragma unroll
    for (int i = 0; i < 4; ++i)
      ld_lds16(pb + (size_t)i * 64 * K + t * 64,
               (char*)Bs + (wid * 8 + i * 64) * 128);
  };

  stage(0, 0);
  stage(1, 1);
  asm volatile("s_waitcnt vmcnt(6)" ::: "memory");   // tile 0 landed
  asm volatile("s_barrier" ::: "memory");

  bf16x8 af[4][2], bb0[2][2], bb1[2][2];

  for (int t = 0; t < KT; ++t) {
    int p = t & 1;
    const unsigned short* As = &Sm[p][0];
    const unsigned short* Bs = &Sm[p][128 * 64];

    // ---- P1: ALL reads (af 8, bb0 4, bb1 4); MFMA (n0,n1) ----------------
#pragma unroll
    for (int mi = 0; mi < 4; ++mi)
#pragma unroll
      for (int kx = 0; kx < 2; ++kx) {
        int row = wr * 64 + mi * 16 + lo;
        int cgx = (quad + kx * 4) ^ (row & 7);
        af[mi][kx] = *(const bf16x8*)(As + (size_t)row * 64 + cgx * 8);
      }
#pragma unroll
    for (int ni = 0; ni < 2; ++ni)
#pragma unroll
      for (int kx = 0; kx < 2; ++kx) {
        int row = wc * 64 + ni * 16 + lo;
        int cgx = (quad + kx * 4) ^ (row & 7);
        bb0[ni][kx] = *(const bf16x8*)(Bs + (size_t)row * 64 + cgx * 8);
      }
#pragma unroll
    for (int ni = 0; ni < 2; ++ni)
#pragma unroll
      for (int kx = 0; kx < 2; ++kx) {
        int row = wc * 64 + (ni + 2) * 16 + lo;
        int cgx = (quad + kx * 4) ^ (row & 7);
        bb1[ni][kx] = *(const bf16x8*)(Bs + (size_t)row * 64 + cgx * 8);
      }
    asm volatile("s_barrier" ::: "memory");
    __builtin_amdgcn_s_setprio(1);
#pragma unroll
    for (int kx = 0; kx < 2; ++kx)
#pragma unroll
      for (int mi = 0; mi < 4; ++mi)
#pragma unroll
        for (int ni = 0; ni < 2; ++ni)
          acc[mi][ni] = mfma16(af[mi][kx], bb0[ni][kx], acc[mi][ni]);
    __builtin_amdgcn_s_setprio(0);
    asm volatile("s_barrier" ::: "memory");

    // ---- P2: prefetch t+2; MFMA (n2,n3) register-only; counted vmcnt -----
    bool pf = (t + 2 < KT);
    if (pf) stage(t + 2, p);
    __builtin_amdgcn_s_setprio(1);
#pragma unroll
    for (int kx = 0; kx < 2; ++kx)
#pragma unroll
      for (int mi = 0; mi < 4; ++mi)
#pragma unroll
        for (int ni = 0; ni < 2; ++ni)
          acc[mi][ni + 2] = mfma16(af[mi][kx], bb1[ni][kx], acc[mi][ni + 2]);
    __builtin_amdgcn_s_setprio(0);
    if (pf) asm volatile("s_waitcnt vmcnt(6)" ::: "memory");
    else    asm volatile("s_waitcnt vmcnt(0)" ::: "memory");
    asm volatile("s_barrier" ::: "memory");
  }

  // epilogue: fp32 out[(b,t,p),col]
#pragma unroll
  for (int mi = 0; mi < 4; ++mi) {
    for (int ni = 0; ni < 4; ++ni) {
      int col = tn * 256 + wc * 64 + ni * 16 + lo;
      for (int r = 0; r < 4; ++r) {
        int grow = tm * 128 + wr * 64 + mi * 16 + quad * 4 + r;
        int bp = grow >> 9, tt = grow & 511;
        int b = bp >> 3, pp = bp & 7;
        out[((((size_t)b * 512 + tt) * 8 + pp) << 10) + col] = acc[mi][ni][r];
      }
    }
  }
}

// ---- attention v3 (r6-verified, neutral-cost ~10us): Q-in-reg, 2 q-sets --
__global__ __launch_bounds__(512, 2) void attn(
    const unsigned short* __restrict__ qbuf, const unsigned short* __restrict__ kb,
    const unsigned short* __restrict__ vtb, unsigned short* __restrict__ ao) {
  __shared__ __align__(16) unsigned short Ks[2][64 * 64];
  __shared__ __align__(16) unsigned short Vs[2][64 * 64];  // V^T: [d][key]

  int tid = threadIdx.x;
  int lane = tid & 63, wid = tid >> 6;                  // wid 0..7
  int lo32 = lane & 31, hl = lane >> 5;
  int wg = (blockIdx.x & 7) * 32 + (blockIdx.x >> 3);   // T1: 256 = 8 x 32
  int head = wg & 15, bp = wg >> 4;
  int kvh = head >> 2;
  int srow = lane >> 3, schunk = lane & 7;

  const unsigned short* kg = kb + ((size_t)bp * 512) * 256 + kvh * 64;
  const unsigned short* vg = vtb + ((size_t)(bp * 4 + kvh)) * 64 * 512;

  const unsigned short* qgA =
      qbuf + ((size_t)(bp * 512 + wid * 64 + lo32)) * 1024 + head * 64;
  bf16x8 qA[4], qB[4];
#pragma unroll
  for (int kkc = 0; kkc < 4; ++kkc) {
    int ch = 2 * kkc + hl;
    qA[kkc] = *(const bf16x8*)(qgA + ch * 8);
    qB[kkc] = *(const bf16x8*)(qgA + (size_t)32 * 1024 + ch * 8);
  }

  auto stageKV = [&](int kt, int p) {   // 64 keys of K and V^T
    int row = wid * 8 + srow;
    int cg = schunk ^ (row & 7);
    ld_lds16(kg + (size_t)(kt * 64 + row) * 256 + cg * 8,
             (char*)&Ks[p][0] + (wid * 8) * 128);
    ld_lds16(vg + (size_t)row * 512 + kt * 64 + cg * 8,
             (char*)&Vs[p][0] + (wid * 8) * 128);
  };

  stageKV(0, 0);
  stageKV(1, 1);
  asm volatile("s_waitcnt vmcnt(2)" ::: "memory");   // tile0 landed
  asm volatile("s_barrier" ::: "memory");

  f32x16 z16 = {0.f};
  f32x16 oA0 = z16, oA1 = z16, oB0 = z16, oB1 = z16;
  float psumA = 0.f, psumB = 0.f;

  for (int kt = 0; kt < 8; ++kt) {
    int p = kt & 1;
    const unsigned short* Kp = &Ks[p][0];
    const unsigned short* Vp = &Vs[p][0];

    f32x16 sA0 = z16, sA1 = z16, sB0 = z16, sB1 = z16;
#pragma unroll
    for (int kkc = 0; kkc < 4; ++kkc) {
      int ch = 2 * kkc + hl;
      bf16x8 kf0 = *(const bf16x8*)(Kp + (size_t)lo32 * 64 + ((ch ^ (lo32 & 7)) * 8));
      bf16x8 kf1 = *(const bf16x8*)(Kp + (size_t)(32 + lo32) * 64 + ((ch ^ (lo32 & 7)) * 8));
      sA0 = mfma32(kf0, qA[kkc], sA0);
      sA1 = mfma32(kf1, qA[kkc], sA1);
      sB0 = mfma32(kf0, qB[kkc], sB0);
      sB1 = mfma32(kf1, qB[kkc], sB1);
    }

#pragma unroll
    for (int t = 0; t < 2; ++t) {
      const f32x16& svA = t ? sA1 : sA0;
      const f32x16& svB = t ? sB1 : sB0;
      unsigned pkA[8], xpA[8], pkB[8], xpB[8];
#pragma unroll
      for (int pp = 0; pp < 8; ++pp) {
        float a0 = __expf(svA[2 * pp]);
        float a1 = __expf(svA[2 * pp + 1]);
        psumA += a0 + a1;
        pkA[pp] = ((__float_as_uint(a0) + 0x8000u) >> 16) |
                  ((__float_as_uint(a1) + 0x8000u) & 0xffff0000u);
        float b0 = __expf(svB[2 * pp]);
        float b1 = __expf(svB[2 * pp + 1]);
        psumB += b0 + b1;
        pkB[pp] = ((__float_as_uint(b0) + 0x8000u) >> 16) |
                  ((__float_as_uint(b1) + 0x8000u) & 0xffff0000u);
      }
#pragma unroll
      for (int pp = 0; pp < 8; ++pp) {
        xpA[pp] = (unsigned)__shfl_xor((int)pkA[pp], 32);
        xpB[pp] = (unsigned)__shfl_xor((int)pkB[pp], 32);
      }
#pragma unroll
      for (int cc = 0; cc < 2; ++cc) {
        int o = cc * 4;
        union { unsigned u[4]; bf16x8 v; } fA, fB;
        if (hl == 0) {
          fA.u[0] = pkA[o];     fA.u[1] = pkA[o + 1];
          fA.u[2] = xpA[o];     fA.u[3] = xpA[o + 1];
          fB.u[0] = pkB[o];     fB.u[1] = pkB[o + 1];
          fB.u[2] = xpB[o];     fB.u[3] = xpB[o + 1];
        } else {
          fA.u[0] = xpA[o + 2]; fA.u[1] = xpA[o + 3];
          fA.u[2] = pkA[o + 2]; fA.u[3] = pkA[o + 3];
          fB.u[0] = xpB[o + 2]; fB.u[1] = xpB[o + 3];
          fB.u[2] = pkB[o + 2]; fB.u[3] = pkB[o + 3];
        }
        int vch = 2 * (t * 2 + cc) + hl;
        bf16x8 v0 = *(const bf16x8*)(Vp + (size_t)lo32 * 64 + ((vch ^ (lo32 & 7)) * 8));
        bf16x8 v1 = *(const bf16x8*)(Vp + (size_t)(32 + lo32) * 64 + ((vch ^ (lo32 & 7)) * 8));
        oA0 = mfma32(fA.v, v0, oA0);
        oA1 = mfma32(fA.v, v1, oA1);
        oB0 = mfma32(fB.v, v0, oB0);
        oB1 = mfma32(fB.v, v1, oB1);
      }
    }

    if (kt == 7) break;
    asm volatile("s_barrier" ::: "memory");            // done reading buf p
    if (kt < 6) {
      stageKV(kt + 2, p);                              // lands under tile kt+1
      asm volatile("s_waitcnt vmcnt(2)" ::: "memory"); // tile kt+1 landed
    } else {
      asm volatile("s_waitcnt vmcnt(0)" ::: "memory"); // tile 7 landed
    }
    asm volatile("s_barrier" ::: "memory");            // publish tile kt+1
  }

  psumA += __shfl_xor(psumA, 32);
  psumB += __shfl_xor(psumB, 32);
  float invA = 1.f / psumA, invB = 1.f / psumB;
#pragma unroll
  for (int r = 0; r < 16; ++r) {
    int q_r = (r & 3) + 8 * (r >> 2) + 4 * hl;
    float scA = __shfl(invA, q_r);   // holder lane lo32=q_r
    float scB = __shfl(invB, q_r);
    size_t gA = (size_t)(bp * 512 + wid * 64 + q_r);
    ao[gA * 1024 + head * 64 + lo32]      = f2bf(oA0[r] * scA);
    ao[gA * 1024 + head * 64 + 32 + lo32] = f2bf(oA1[r] * scA);
    size_t gB = gA + 32;
    ao[gB * 1024 + head * 64 + lo32]      = f2bf(oB0[r] * scB);
    ao[gB * 1024 + head * 64 + 32 + lo32] = f2bf(oB1[r] * scB);
  }
}

extern "C" void kernel_launch(void* const* d_in, const int* in_sizes, int n_in,
                              void* d_out, int out_size, void* d_ws, size_t ws_size,
                              hipStream_t stream) {
  const float* hs = (const float*)d_in[0];
  const float* Wq = (const float*)d_in[1];
  const float* Wk = (const float*)d_in[2];
  const float* Wv = (const float*)d_in[3];
  const float* Wo = (const float*)d_in[4];
  float* out = (float*)d_out;

  unsigned short* xb   = (unsigned short*)d_ws;                 // 8192*1024
  unsigned short* wqkv = xb + (size_t)8192 * 1024;              // 1536*1024
  unsigned short* wot  = wqkv + (size_t)1536 * 1024;            // 1024*1024
  unsigned short* qbuf = wot + (size_t)1024 * 1024;             // 8192*1024
  unsigned short* kbuf = qbuf + (size_t)8192 * 1024;            // 8192*256
  unsigned short* vtb  = kbuf + (size_t)8192 * 256;             // 8192*256
  unsigned short* ao   = xb;                                    // alias

  conv_all<<<8832, 256, 0, stream>>>(hs, Wq, Wk, Wv, Wo, xb, wqkv, wot);
  gemm_qkv<<<192, 512, 0, stream>>>(xb, wqkv, qbuf, kbuf, vtb);
  attn<<<256, 512, 0, stream>>>(qbuf, kbuf, vtb, ao);
  gemm_o<<<256, 512, 0, stream>>>(ao, wot, out);
}

// Round 9
// 175.109 us; speedup vs baseline: 1.6716x; 1.0092x over previous
//
#include <hip/hip_runtime.h>
#include <stdint.h>

// Problem constants: B=2, T=512, P=8, D=1024, NH=16, NKV=4, HD=64
// Rows (b,p,t): 16*512 = 8192.

typedef __attribute__((ext_vector_type(8))) short bf16x8;
typedef __attribute__((ext_vector_type(4))) float f32x4;
typedef __attribute__((ext_vector_type(16))) float f32x16;
typedef __attribute__((ext_vector_type(4))) unsigned short us4;
typedef __attribute__((ext_vector_type(8))) unsigned short us8;

static __device__ __forceinline__ unsigned short f2bf(float f) {
  unsigned u = __float_as_uint(f);
  u += 0x7fffu + ((u >> 16) & 1u);   // RNE
  return (unsigned short)(u >> 16);
}

static __device__ __forceinline__ void ld_lds16(const void* g, void* l) {
  __builtin_amdgcn_global_load_lds(
      (const __attribute__((address_space(1))) void*)g,
      (__attribute__((address_space(3))) void*)l, 16, 0, 0);
}

static __device__ __forceinline__ f32x4 mfma16(bf16x8 a, bf16x8 b, f32x4 c) {
  return __builtin_amdgcn_mfma_f32_16x16x32_bf16(a, b, c, 0, 0, 0);
}
static __device__ __forceinline__ f32x16 mfma32(bf16x8 a, bf16x8 b, f32x16 c) {
  return __builtin_amdgcn_mfma_f32_32x32x16_bf16(a, b, c, 0, 0, 0);
}

// ---- fused conversions: blocks 0..8191 pack x; 8192..8831 transpose W ----
// Wq/Wk output rows are PAIR-INTERLEAVED within each 64-col head-block:
// physical 2k <- logical d=k, physical 2k+1 <- logical d=k+32. This makes
// RoPE pairs adjacent lanes in the GEMM epilogue (shfl_xor(1)). Q and K get
// the SAME permutation, so attn's QK^T dot products are unchanged.
__global__ __launch_bounds__(256) void conv_all(
    const float* __restrict__ hs, const float* __restrict__ Wq,
    const float* __restrict__ Wk, const float* __restrict__ Wv,
    const float* __restrict__ Wo, unsigned short* __restrict__ xb,
    unsigned short* __restrict__ wqkv, unsigned short* __restrict__ wot) {
  __shared__ float tile[64][65];
  int bid = blockIdx.x, tid = threadIdx.x;
  if (bid < 8192) {
    int gid = bid * 256 + tid;
    size_t e = (size_t)gid * 4;
    int r = (int)(e >> 10);          // bp*512 + t
    int d = (int)(e & 1023);
    int b = r >> 12, p = (r >> 9) & 7, t = r & 511;
    const float4* src = (const float4*)(hs + ((((size_t)b * 512 + t) * 8 + p) << 10) + d);
    float4 v = *src;
    us4 o;
    o.x = f2bf(v.x); o.y = f2bf(v.y); o.z = f2bf(v.z); o.w = f2bf(v.w);
    *(us4*)(xb + e) = o;
    return;
  }
  int tb = bid - 8192;
  const float* W; unsigned short* Wt; int N, tc0, tn0;
  if (tb < 256)      { W = Wq; Wt = wqkv;                       N = 1024; tc0 = (tb >> 4) * 64;          tn0 = (tb & 15) * 64; }
  else if (tb < 320) { W = Wk; Wt = wqkv + (size_t)1024 * 1024; N = 256;  tc0 = ((tb - 256) >> 2) * 64;  tn0 = ((tb - 256) & 3) * 64; }
  else if (tb < 384) { W = Wv; Wt = wqkv + (size_t)1280 * 1024; N = 256;  tc0 = ((tb - 320) >> 2) * 64;  tn0 = ((tb - 320) & 3) * 64; }
  else               { W = Wo; Wt = wot;                        N = 1024; tc0 = ((tb - 384) >> 4) * 64;  tn0 = ((tb - 384) & 15) * 64; }
  bool il = (tb < 320);              // interleave Q and K head-blocks
  int tr = tid >> 4, tc = tid & 15;
#pragma unroll
  for (int i = 0; i < 4; ++i) {
    int c = tr + i * 16;
    float4 v = *(const float4*)(W + (size_t)(tc0 + c) * N + tn0 + tc * 4);
    tile[c][tc * 4 + 0] = v.x; tile[c][tc * 4 + 1] = v.y;
    tile[c][tc * 4 + 2] = v.z; tile[c][tc * 4 + 3] = v.w;
  }
  __syncthreads();
#pragma unroll
  for (int i = 0; i < 4; ++i) {
    int n = tr + i * 16;
    us4 o;
    o.x = f2bf(tile[tc * 4 + 0][n]); o.y = f2bf(tile[tc * 4 + 1][n]);
    o.z = f2bf(tile[tc * 4 + 2][n]); o.w = f2bf(tile[tc * 4 + 3][n]);
    int p = il ? ((n < 32) ? n * 2 : (n - 32) * 2 + 1) : n;
    *(us4*)(Wt + (size_t)(tn0 + p) * 1024 + tc0 + tc * 4) = o;
  }
}

// ---- 128x384x(K=1024) QKV GEMM: 64x4 = 256 blocks = 100% grid fill ------
// r7 budget: old 256^2 kernel left 64 CUs idle (192 blocks). Equal-work
// 100.6MF tiles = 128x384 (384 = 6 head-blocks). Waves 2x4 (64x96 each) ->
// LDS reads:MFMA = 20:48, enabled by conv's pair-interleaved Wq/Wk layout
// (RoPE pair = adjacent lanes, rotated via shfl_xor(1) in epilogue).
// 2-phase K-loop (gemm_o pattern): P1 {af+bb(0..2) reads; bar; 24 MFMA;
// bar}, P2 {bb(3..5) reads; lgkmcnt(0); bar; prefetch t+2; 24 MFMA reg-only;
// vmcnt(8); bar}. Typed epilogue per 64-col block: Q (*0.125) / K -> RoPE
// + Cs stage; V -> Cv transpose stage; coalesced us8 stores.
__global__ __launch_bounds__(512, 2) void gemm_qkv(
    const unsigned short* __restrict__ A, const unsigned short* __restrict__ Bt,
    unsigned short* __restrict__ qb, unsigned short* __restrict__ kb,
    unsigned short* __restrict__ vtb) {
  constexpr int K = 1024;
  constexpr int KT = K / 64;
  __shared__ __align__(16) unsigned short Sm[2][(128 + 384) * 64];  // 128 KiB
  unsigned short* Cs = &Sm[0][0];

  int tid = threadIdx.x;
  int lane = tid & 63, wid = tid >> 6;
  int quad = lane >> 4, lo = lane & 15;
  int wg = (blockIdx.x & 7) * 32 + (blockIdx.x >> 3);   // T1: 256 = 8 x 32
  int tn = wg & 3, tm = wg >> 2;                        // tm 0..63, tn 0..3
  int wr = wid >> 2, wc = wid & 3;                      // waves 2x4
  int srow = lane >> 3, schunk = lane & 7;
  int cg = schunk ^ srow;

  const unsigned short* pa = A + ((size_t)(tm * 128) + wid * 8 + srow) * K + cg * 8;
  const unsigned short* pb = Bt + ((size_t)(tn * 384) + wid * 8 + srow) * K + cg * 8;

  f32x4 z = {0.f, 0.f, 0.f, 0.f};
  f32x4 acc[4][6];
#pragma unroll
  for (int i = 0; i < 4; ++i)
#pragma unroll
    for (int j = 0; j < 6; ++j) acc[i][j] = z;

  auto stage = [&](int t, int p) {
    unsigned short* As_ = &Sm[p][0];
    unsigned short* Bs_ = &Sm[p][128 * 64];
#pragma unroll
    for (int i = 0; i < 2; ++i)
      ld_lds16(pa + (size_t)i * 64 * K + t * 64, (char*)As_ + (wid * 8 + i * 64) * 128);
#pragma unroll
    for (int i = 0; i < 6; ++i)
      ld_lds16(pb + (size_t)i * 64 * K + t * 64, (char*)Bs_ + (wid * 8 + i * 64) * 128);
  };

  stage(0, 0);
  stage(1, 1);
  asm volatile("s_waitcnt vmcnt(8)" ::: "memory");   // tile 0 landed
  asm volatile("s_barrier" ::: "memory");

  bf16x8 af[4][2], bb[3][2];

  for (int t = 0; t < KT; ++t) {
    int p = t & 1;
    const unsigned short* As = &Sm[p][0];
    const unsigned short* Bs = &Sm[p][128 * 64];

    // ---- P1: af (8) + bb ni0..2 (6); MFMA ni0..2 -------------------------
#pragma unroll
    for (int mi = 0; mi < 4; ++mi)
#pragma unroll
      for (int kx = 0; kx < 2; ++kx) {
        int row = wr * 64 + mi * 16 + lo;
        int cgx = (quad + kx * 4) ^ (row & 7);
        af[mi][kx] = *(const bf16x8*)(As + (size_t)row * 64 + cgx * 8);
      }
#pragma unroll
    for (int ni = 0; ni < 3; ++ni)
#pragma unroll
      for (int kx = 0; kx < 2; ++kx) {
        int row = wc * 96 + ni * 16 + lo;
        int cgx = (quad + kx * 4) ^ (row & 7);
        bb[ni][kx] = *(const bf16x8*)(Bs + (size_t)row * 64 + cgx * 8);
      }
    asm volatile("s_barrier" ::: "memory");
    __builtin_amdgcn_s_setprio(1);
#pragma unroll
    for (int kx = 0; kx < 2; ++kx)
#pragma unroll
      for (int mi = 0; mi < 4; ++mi)
#pragma unroll
        for (int ni = 0; ni < 3; ++ni)
          acc[mi][ni] = mfma16(af[mi][kx], bb[ni][kx], acc[mi][ni]);
    __builtin_amdgcn_s_setprio(0);
    asm volatile("s_barrier" ::: "memory");

    // ---- P2: bb ni3..5 (6); drain; prefetch t+2; MFMA ni3..5 reg-only ----
#pragma unroll
    for (int ni = 0; ni < 3; ++ni)
#pragma unroll
      for (int kx = 0; kx < 2; ++kx) {
        int row = wc * 96 + (ni + 3) * 16 + lo;
        int cgx = (quad + kx * 4) ^ (row & 7);
        bb[ni][kx] = *(const bf16x8*)(Bs + (size_t)row * 64 + cgx * 8);
      }
    asm volatile("s_waitcnt lgkmcnt(0)" ::: "memory");  // reads retired
    __builtin_amdgcn_sched_barrier(0);
    asm volatile("s_barrier" ::: "memory");             // all waves retired
    bool pf = (t + 2 < KT);
    if (pf) stage(t + 2, p);
    __builtin_amdgcn_s_setprio(1);
#pragma unroll
    for (int kx = 0; kx < 2; ++kx)
#pragma unroll
      for (int mi = 0; mi < 4; ++mi)
#pragma unroll
        for (int ni = 0; ni < 3; ++ni)
          acc[mi][ni + 3] = mfma16(af[mi][kx], bb[ni][kx], acc[mi][ni + 3]);
    __builtin_amdgcn_s_setprio(0);
    if (pf) asm volatile("s_waitcnt vmcnt(8)" ::: "memory");
    else    asm volatile("s_waitcnt vmcnt(0)" ::: "memory");
    asm volatile("s_barrier" ::: "memory");
  }
  __syncthreads();

  // ---- epilogue: per-64-block typing. blkg = tn*6 + col/64:
  //   <16 Q (RoPE, *0.125) ; <20 K (RoPE) ; else V (transpose).
  int Ws = (tn == 3) ? 128 : 384;          // compact K region for tile 3
  unsigned short* Cv = Cs + 128 * 128;     // V region (tile 3 only)
  float sgn = (lane & 1) ? 1.f : -1.f;     // interleaved-RoPE sign
#pragma unroll
  for (int ni = 0; ni < 6; ++ni) {
    int colb = wc * 96 + ni * 16;          // 16-aligned local col base
    int blkg = tn * 6 + (colb >> 6);
    if (blkg < 20) {
      float qs = (blkg < 16) ? 0.125f : 1.0f;
      int kidx = ((colb & 63) + lo) >> 1;  // rotation index 0..31
      float invf = exp2f((float)kidx * -0.41524101186092029f);
      int col = colb + lo;
#pragma unroll
      for (int mi = 0; mi < 4; ++mi)
#pragma unroll
        for (int r = 0; r < 4; ++r) {
          int row = wr * 64 + mi * 16 + quad * 4 + r;
          int tpos = (tm * 128 + row) & 511;
          float ang = (float)tpos * invf;
          float s, c;
          __sincosf(ang, &s, &c);
          float x = acc[mi][ni][r];
          float xo = __shfl_xor(x, 1);     // pair value (adjacent lane)
          float out = (x * c + sgn * xo * s) * qs;
          Cs[row * Ws + (col ^ (((row >> 2) & 3) << 3))] = f2bf(out);
        }
    } else {
      int cv = colb + lo - 128;            // V-local col 0..255
#pragma unroll
      for (int mi = 0; mi < 4; ++mi)
#pragma unroll
        for (int r = 0; r < 4; ++r) {
          int trow = wr * 64 + mi * 16 + quad * 4 + r;
          Cv[cv * 128 + (trow ^ ((cv & 7) << 3))] = f2bf(acc[mi][ni][r]);
        }
    }
  }
  __syncthreads();

  if (tn < 3) {
#pragma unroll
    for (int it = 0; it < 12; ++it) {
      int linear = it * 512 + tid;          // 128 rows x 48 chunks
      int row = linear / 48, ch = linear % 48;
      int cs = (ch * 8) ^ (((row >> 2) & 3) << 3);
      us8 v = *(const us8*)(Cs + row * 384 + cs);
      int g = tn * 384 + ch * 8;
      size_t grow = (size_t)(tm * 128 + row);
      if (g < 1024) *(us8*)(qb + grow * 1024 + g) = v;
      else          *(us8*)(kb + grow * 256 + (g - 1024)) = v;
    }
  } else {
#pragma unroll
    for (int it = 0; it < 4; ++it) {
      int linear = it * 512 + tid;          // 128 rows x 16 chunks (K part)
      int row = linear >> 4, ch = linear & 15;
      int cs = (ch * 8) ^ (((row >> 2) & 3) << 3);
      us8 v = *(const us8*)(Cs + row * 128 + cs);
      size_t grow = (size_t)(tm * 128 + row);
      *(us8*)(kb + grow * 256 + 128 + ch * 8) = v;
    }
    int chunk = tid & 15, colIdx = tid >> 4;
    int bp = tm >> 2, tbase = (tm & 3) * 128;
#pragma unroll
    for (int it = 0; it < 8; ++it) {        // V part: 256 cols x 128 t
      int col = colIdx + 32 * it;
      int t0 = chunk * 8;
      us8 v = *(const us8*)(Cv + col * 128 + (t0 ^ ((col & 7) << 3)));
      int hh = col >> 6, dd = col & 63;
      *(us8*)(vtb + (((size_t)(bp * 4 + hh)) * 64 + dd) * 512 + tbase + t0) = v;
    }
  }
}

// ---- 128x256x(K=1024) O-proj GEMM, v2 (r7-verified): no dead phase ------
__global__ __launch_bounds__(512, 2) void gemm_o(
    const unsigned short* __restrict__ A, const unsigned short* __restrict__ Bt,
    float* __restrict__ out) {
  constexpr int K = 1024;
  constexpr int KT = K / 64;
  __shared__ __align__(16) unsigned short Sm[2][(128 + 256) * 64];

  int tid = threadIdx.x;
  int lane = tid & 63, wid = tid >> 6;
  int quad = lane >> 4, lo = lane & 15;
  int wg = (blockIdx.x & 7) * 32 + (blockIdx.x >> 3);   // T1: 256 = 8 x 32
  int tn = wg & 3, tm = wg >> 2;                        // tm 0..63, tn 0..3
  int wr = wid >> 2, wc = wid & 3;
  int srow = lane >> 3, schunk = lane & 7;
  int cg = schunk ^ srow;

  const unsigned short* pa = A + ((size_t)(tm * 128) + wid * 8 + srow) * K + cg * 8;
  const unsigned short* pb = Bt + ((size_t)(tn * 256) + wid * 8 + srow) * K + cg * 8;

  f32x4 z = {0.f, 0.f, 0.f, 0.f};
  f32x4 acc[4][4];
#pragma unroll
  for (int i = 0; i < 4; ++i)
#pragma unroll
    for (int j = 0; j < 4; ++j) acc[i][j] = z;

  auto stage = [&](int t, int p) {
    unsigned short* As = &Sm[p][0];
    unsigned short* Bs = &Sm[p][128 * 64];
#pragma unroll
    for (int i = 0; i < 2; ++i)
      ld_lds16(pa + (size_t)i * 64 * K + t * 64,
               (char*)As + (wid * 8 + i * 64) * 128);
#pragma unroll
    for (int i = 0; i < 4; ++i)
      ld_lds16(pb + (size_t)i * 64 * K + t * 64,
               (char*)Bs + (wid * 8 + i * 64) * 128);
  };

  stage(0, 0);
  stage(1, 1);
  asm volatile("s_waitcnt vmcnt(6)" ::: "memory");   // tile 0 landed
  asm volatile("s_barrier" ::: "memory");

  bf16x8 af[4][2], bb0[2][2], bb1[2][2];

  for (int t = 0; t < KT; ++t) {
    int p = t & 1;
    const unsigned short* As = &Sm[p][0];
    const unsigned short* Bs = &Sm[p][128 * 64];

    // ---- P1: ALL reads (af 8, bb0 4, bb1 4); MFMA (n0,n1) ----------------
#pragma unroll
    for (int mi = 0; mi < 4; ++mi)
#pragma unroll
      for (int kx = 0; kx < 2; ++kx) {
        int row = wr * 64 + mi * 16 + lo;
        int cgx = (quad + kx * 4) ^ (row & 7);
        af[mi][kx] = *(const bf16x8*)(As + (size_t)row * 64 + cgx * 8);
      }
#pragma unroll
    for (int ni = 0; ni < 2; ++ni)
#pragma unroll
      for (int kx = 0; kx < 2; ++kx) {
        int row = wc * 64 + ni * 16 + lo;
        int cgx = (quad + kx * 4) ^ (row & 7);
        bb0[ni][kx] = *(const bf16x8*)(Bs + (size_t)row * 64 + cgx * 8);
      }
#pragma unroll
    for (int ni = 0; ni < 2; ++ni)
#pragma unroll
      for (int kx = 0; kx < 2; ++kx) {
        int row = wc * 64 + (ni + 2) * 16 + lo;
        int cgx = (quad + kx * 4) ^ (row & 7);
        bb1[ni][kx] = *(const bf16x8*)(Bs + (size_t)row * 64 + cgx * 8);
      }
    asm volatile("s_barrier" ::: "memory");
    __builtin_amdgcn_s_setprio(1);
#pragma unroll
    for (int kx = 0; kx < 2; ++kx)
#pragma unroll
      for (int mi = 0; mi < 4; ++mi)
#pragma unroll
        for (int ni = 0; ni < 2; ++ni)
          acc[mi][ni] = mfma16(af[mi][kx], bb0[ni][kx], acc[mi][ni]);
    __builtin_amdgcn_s_setprio(0);
    asm volatile("s_barrier" ::: "memory");

    // ---- P2: prefetch t+2; MFMA (n2,n3) register-only; counted vmcnt -----
    bool pf = (t + 2 < KT);
    if (pf) stage(t + 2, p);
    __builtin_amdgcn_s_setprio(1);
#pragma unroll
    for (int kx = 0; kx < 2; ++kx)
#pragma unroll
      for (int mi = 0; mi < 4; ++mi)
#pragma unroll
        for (int ni = 0; ni < 2; ++ni)
          acc[mi][ni + 2] = mfma16(af[mi][kx], bb1[ni][kx], acc[mi][ni + 2]);
    __builtin_amdgcn_s_setprio(0);
    if (pf) asm volatile("s_waitcnt vmcnt(6)" ::: "memory");
    else    asm volatile("s_waitcnt vmcnt(0)" ::: "memory");
    asm volatile("s_barrier" ::: "memory");
  }

  // epilogue: fp32 out[(b,t,p),col]
#pragma unroll
  for (int mi = 0; mi < 4; ++mi) {
    for (int ni = 0; ni < 4; ++ni) {
      int col = tn * 256 + wc * 64 + ni * 16 + lo;
      for (int r = 0; r < 4; ++r) {
        int grow = tm * 128 + wr * 64 + mi * 16 + quad * 4 + r;
        int bp = grow >> 9, tt = grow & 511;
        int b = bp >> 3, pp = bp & 7;
        out[((((size_t)b * 512 + tt) * 8 + pp) << 10) + col] = acc[mi][ni][r];
      }
    }
  }
}

// ---- attention v3 (r6-verified): Q-in-reg, 2 q-sets, dbuf K/V ------------
__global__ __launch_bounds__(512, 2) void attn(
    const unsigned short* __restrict__ qbuf, const unsigned short* __restrict__ kb,
    const unsigned short* __restrict__ vtb, unsigned short* __restrict__ ao) {
  __shared__ __align__(16) unsigned short Ks[2][64 * 64];
  __shared__ __align__(16) unsigned short Vs[2][64 * 64];  // V^T: [d][key]

  int tid = threadIdx.x;
  int lane = tid & 63, wid = tid >> 6;                  // wid 0..7
  int lo32 = lane & 31, hl = lane >> 5;
  int wg = (blockIdx.x & 7) * 32 + (blockIdx.x >> 3);   // T1: 256 = 8 x 32
  int head = wg & 15, bp = wg >> 4;
  int kvh = head >> 2;
  int srow = lane >> 3, schunk = lane & 7;

  const unsigned short* kg = kb + ((size_t)bp * 512) * 256 + kvh * 64;
  const unsigned short* vg = vtb + ((size_t)(bp * 4 + kvh)) * 64 * 512;

  const unsigned short* qgA =
      qbuf + ((size_t)(bp * 512 + wid * 64 + lo32)) * 1024 + head * 64;
  bf16x8 qA[4], qB[4];
#pragma unroll
  for (int kkc = 0; kkc < 4; ++kkc) {
    int ch = 2 * kkc + hl;
    qA[kkc] = *(const bf16x8*)(qgA + ch * 8);
    qB[kkc] = *(const bf16x8*)(qgA + (size_t)32 * 1024 + ch * 8);
  }

  auto stageKV = [&](int kt, int p) {   // 64 keys of K and V^T
    int row = wid * 8 + srow;
    int cg = schunk ^ (row & 7);
    ld_lds16(kg + (size_t)(kt * 64 + row) * 256 + cg * 8,
             (char*)&Ks[p][0] + (wid * 8) * 128);
    ld_lds16(vg + (size_t)row * 512 + kt * 64 + cg * 8,
             (char*)&Vs[p][0] + (wid * 8) * 128);
  };

  stageKV(0, 0);
  stageKV(1, 1);
  asm volatile("s_waitcnt vmcnt(2)" ::: "memory");   // tile0 landed
  asm volatile("s_barrier" ::: "memory");

  f32x16 z16 = {0.f};
  f32x16 oA0 = z16, oA1 = z16, oB0 = z16, oB1 = z16;
  float psumA = 0.f, psumB = 0.f;

  for (int kt = 0; kt < 8; ++kt) {
    int p = kt & 1;
    const unsigned short* Kp = &Ks[p][0];
    const unsigned short* Vp = &Vs[p][0];

    f32x16 sA0 = z16, sA1 = z16, sB0 = z16, sB1 = z16;
#pragma unroll
    for (int kkc = 0; kkc < 4; ++kkc) {
      int ch = 2 * kkc + hl;
      bf16x8 kf0 = *(const bf16x8*)(Kp + (size_t)lo32 * 64 + ((ch ^ (lo32 & 7)) * 8));
      bf16x8 kf1 = *(const bf16x8*)(Kp + (size_t)(32 + lo32) * 64 + ((ch ^ (lo32 & 7)) * 8));
      sA0 = mfma32(kf0, qA[kkc], sA0);
      sA1 = mfma32(kf1, qA[kkc], sA1);
      sB0 = mfma32(kf0, qB[kkc], sB0);
      sB1 = mfma32(kf1, qB[kkc], sB1);
    }

#pragma unroll
    for (int t = 0; t < 2; ++t) {
      const f32x16& svA = t ? sA1 : sA0;
      const f32x16& svB = t ? sB1 : sB0;
      unsigned pkA[8], xpA[8], pkB[8], xpB[8];
#pragma unroll
      for (int pp = 0; pp < 8; ++pp) {
        float a0 = __expf(svA[2 * pp]);
        float a1 = __expf(svA[2 * pp + 1]);
        psumA += a0 + a1;
        pkA[pp] = ((__float_as_uint(a0) + 0x8000u) >> 16) |
                  ((__float_as_uint(a1) + 0x8000u) & 0xffff0000u);
        float b0 = __expf(svB[2 * pp]);
        float b1 = __expf(svB[2 * pp + 1]);
        psumB += b0 + b1;
        pkB[pp] = ((__float_as_uint(b0) + 0x8000u) >> 16) |
                  ((__float_as_uint(b1) + 0x8000u) & 0xffff0000u);
      }
#pragma unroll
      for (int pp = 0; pp < 8; ++pp) {
        xpA[pp] = (unsigned)__shfl_xor((int)pkA[pp], 32);
        xpB[pp] = (unsigned)__shfl_xor((int)pkB[pp], 32);
      }
#pragma unroll
      for (int cc = 0; cc < 2; ++cc) {
        int o = cc * 4;
        union { unsigned u[4]; bf16x8 v; } fA, fB;
        if (hl == 0) {
          fA.u[0] = pkA[o];     fA.u[1] = pkA[o + 1];
          fA.u[2] = xpA[o];     fA.u[3] = xpA[o + 1];
          fB.u[0] = pkB[o];     fB.u[1] = pkB[o + 1];
          fB.u[2] = xpB[o];     fB.u[3] = xpB[o + 1];
        } else {
          fA.u[0] = xpA[o + 2]; fA.u[1] = xpA[o + 3];
          fA.u[2] = pkA[o + 2]; fA.u[3] = pkA[o + 3];
          fB.u[0] = xpB[o + 2]; fB.u[1] = xpB[o + 3];
          fB.u[2] = pkB[o + 2]; fB.u[3] = pkB[o + 3];
        }
        int vch = 2 * (t * 2 + cc) + hl;
        bf16x8 v0 = *(const bf16x8*)(Vp + (size_t)lo32 * 64 + ((vch ^ (lo32 & 7)) * 8));
        bf16x8 v1 = *(const bf16x8*)(Vp + (size_t)(32 + lo32) * 64 + ((vch ^ (lo32 & 7)) * 8));
        oA0 = mfma32(fA.v, v0, oA0);
        oA1 = mfma32(fA.v, v1, oA1);
        oB0 = mfma32(fB.v, v0, oB0);
        oB1 = mfma32(fB.v, v1, oB1);
      }
    }

    if (kt == 7) break;
    asm volatile("s_barrier" ::: "memory");            // done reading buf p
    if (kt < 6) {
      stageKV(kt + 2, p);                              // lands under tile kt+1
      asm volatile("s_waitcnt vmcnt(2)" ::: "memory"); // tile kt+1 landed
    } else {
      asm volatile("s_waitcnt vmcnt(0)" ::: "memory"); // tile 7 landed
    }
    asm volatile("s_barrier" ::: "memory");            // publish tile kt+1
  }

  psumA += __shfl_xor(psumA, 32);
  psumB += __shfl_xor(psumB, 32);
  float invA = 1.f / psumA, invB = 1.f / psumB;
#pragma unroll
  for (int r = 0; r < 16; ++r) {
    int q_r = (r & 3) + 8 * (r >> 2) + 4 * hl;
    float scA = __shfl(invA, q_r);   // holder lane lo32=q_r
    float scB = __shfl(invB, q_r);
    size_t gA = (size_t)(bp * 512 + wid * 64 + q_r);
    ao[gA * 1024 + head * 64 + lo32]      = f2bf(oA0[r] * scA);
    ao[gA * 1024 + head * 64 + 32 + lo32] = f2bf(oA1[r] * scA);
    size_t gB = gA + 32;
    ao[gB * 1024 + head * 64 + lo32]      = f2bf(oB0[r] * scB);
    ao[gB * 1024 + head * 64 + 32 + lo32] = f2bf(oB1[r] * scB);
  }
}

extern "C" void kernel_launch(void* const* d_in, const int* in_sizes, int n_in,
                              void* d_out, int out_size, void* d_ws, size_t ws_size,
                              hipStream_t stream) {
  const float* hs = (const float*)d_in[0];
  const float* Wq = (const float*)d_in[1];
  const float* Wk = (const float*)d_in[2];
  const float* Wv = (const float*)d_in[3];
  const float* Wo = (const float*)d_in[4];
  float* out = (float*)d_out;

  unsigned short* xb   = (unsigned short*)d_ws;                 // 8192*1024
  unsigned short* wqkv = xb + (size_t)8192 * 1024;              // 1536*1024
  unsigned short* wot  = wqkv + (size_t)1536 * 1024;            // 1024*1024
  unsigned short* qbuf = wot + (size_t)1024 * 1024;             // 8192*1024
  unsigned short* kbuf = qbuf + (size_t)8192 * 1024;            // 8192*256
  unsigned short* vtb  = kbuf + (size_t)8192 * 256;             // 8192*256
  unsigned short* ao   = xb;                                    // alias

  conv_all<<<8832, 256, 0, stream>>>(hs, Wq, Wk, Wv, Wo, xb, wqkv, wot);
  gemm_qkv<<<256, 512, 0, stream>>>(xb, wqkv, qbuf, kbuf, vtb);
  attn<<<256, 512, 0, stream>>>(qbuf, kbuf, vtb, ao);
  gemm_o<<<256, 512, 0, stream>>>(ao, wot, out);
}